// Round 1
// 2605.409 us; speedup vs baseline: 1.4387x; 1.4387x over previous
//
#include <hip/hip_runtime.h>
#include <hip/hip_bf16.h>

using bf16 = __hip_bfloat16;

namespace {
constexpr int B = 4, T = 512, V = 576, L = 256, H = 1024, NH = 16, HD = 64, I = 4096, E = 8;
constexpr int KT = 80;          // int(1.25*512 + 7) // 8 = 80
constexpr int KI = 90;          // int(1.25*576 + 7) // 8 = 90
constexpr int PBT = B * KT;     // 320
constexpr int PBI = B * KI;     // 360

constexpr size_t FQ   = (size_t)B * T * H;   // 2,097,152
constexpr size_t FIMG = (size_t)B * V * H;   // 2,359,296
constexpr size_t FQKV = FQ + (size_t)B * V * 2 * H;  // 6,815,744
constexpr size_t FHB  = (size_t)E * PBI * I;         // 11,796,480 (bf16 elems in MoE phase)

// small-weight (fp32-converted) region offsets
constexpr size_t sSA_B_IN = 0, sSA_B_OUT = 3072, sCA_B_IN = 4096, sCA_B_OUT = 7168;
constexpr size_t sGIW = 8192, sGIB = 24576, sGTW = 24584, sGTB = 40968;
constexpr size_t sEB1 = 40976, sEB2 = 73744;
constexpr size_t sLNQG = 81936, sLNQB = 82960, sLNCG = 83984, sLNCB = 85008, sLNFG = 86032, sLNFB = 87056;
constexpr size_t SWN = 88080;

// ws layout (float offsets)
constexpr size_t oQ = 0, oXN = oQ + FQ, oAO = oXN + FQ, oIMG = oAO + FIMG;
constexpr size_t oCTXI = oIMG + FIMG, oCTXT = oCTXI + (size_t)B * H;
constexpr size_t oPRT = oCTXT + (size_t)B * H, oPRI = oPRT + (size_t)B * T * E;
constexpr size_t oSW = oPRI + (size_t)B * V * E;
constexpr size_t oINT = oSW + SWN;                      // int region (flag + pairs + counts)
constexpr size_t oBIG = oINT + 16384;                   // QKV(f32) / HB(bf16) union
constexpr size_t WS_FLOATS = oBIG + (FQKV > FHB ? FQKV : FHB);
}

typedef __attribute__((ext_vector_type(8))) short bf16x8;
typedef __attribute__((ext_vector_type(4))) float f32x4;
typedef __attribute__((ext_vector_type(4))) int i32x4;

__device__ __forceinline__ float b2f(bf16 x) { return __bfloat162float(x); }

__device__ __forceinline__ float ldany(const void* p, int f32, size_t idx) {
  return f32 ? ((const float*)p)[idx] : b2f(((const bf16*)p)[idx]);
}

__device__ __forceinline__ unsigned int f2bf_u(float v) {   // RNE fp32->bf16 bits
  unsigned int u = __float_as_uint(v);
  u += 0x7FFFu + ((u >> 16) & 1u);
  return u >> 16;
}
__device__ __forceinline__ int pack2(float a, float b) {
  return (int)(f2bf_u(a) | (f2bf_u(b) << 16));
}

__device__ __forceinline__ float gelu_f(float x) {
  float x3 = x * x * x;
  return 0.5f * x * (1.f + tanhf(0.7978845608028654f * (x + 0.044715f * x3)));
}

// ---------------- dtype probe ----------------
__global__ __launch_bounds__(256) void k_detect(const void* __restrict__ q, int* __restrict__ flag) {
  __shared__ int cnt;
  if (threadIdx.x == 0) cnt = 0;
  __syncthreads();
  int local = 0;
  for (int i = threadIdx.x; i < 65536; i += 256) {
    float v = b2f(((const bf16*)q)[i]);
    if (!(fabsf(v) < 1e4f)) local++;
  }
  atomicAdd(&cnt, local);
  __syncthreads();
  if (threadIdx.x == 0) *flag = (cnt > 64) ? 1 : 0;
}

__global__ __launch_bounds__(256) void k_cvt2(const void* __restrict__ in, float* __restrict__ out,
                                              int n, const int* __restrict__ flag) {
  int f32 = *flag;
  int i = blockIdx.x * 256 + threadIdx.x;
  if (i < n) out[i] = ldany(in, f32, (size_t)i);
}

__global__ __launch_bounds__(256) void k_zerof(float* __restrict__ p, int n) {
  int i = blockIdx.x * 256 + threadIdx.x;
  if (i < n) p[i] = 0.f;
}
__global__ __launch_bounds__(256) void k_zeroi(int* __restrict__ p, int n) {
  int i = blockIdx.x * 256 + threadIdx.x;
  if (i < n) p[i] = 0;
}
__global__ __launch_bounds__(256) void k_diag(float* __restrict__ out, int n, float code) {
  int i = blockIdx.x * 256 + threadIdx.x;
  if (i < n) out[i] = (i == 0 ? code : 0.f);
}

// ---------------- LayerNorm ----------------
__global__ __launch_bounds__(256) void k_ln(const float* __restrict__ X,
                                            const float* __restrict__ g, const float* __restrict__ bta,
                                            float* __restrict__ Y) {
  int row = blockIdx.x;
  const float* x = X + (size_t)row * H;
  float s = 0.f, ss = 0.f;
  for (int j = threadIdx.x; j < H; j += 256) { float v = x[j]; s += v; ss += v * v; }
#pragma unroll
  for (int off = 32; off; off >>= 1) { s += __shfl_xor(s, off); ss += __shfl_xor(ss, off); }
  __shared__ float ls[4], lss[4];
  __shared__ float mean_s, inv_s;
  int w = threadIdx.x >> 6, lane = threadIdx.x & 63;
  if (lane == 0) { ls[w] = s; lss[w] = ss; }
  __syncthreads();
  if (threadIdx.x == 0) {
    float S1 = ls[0] + ls[1] + ls[2] + ls[3];
    float S2 = lss[0] + lss[1] + lss[2] + lss[3];
    float m = S1 / (float)H;
    float var = S2 / (float)H - m * m;
    mean_s = m;
    inv_s = 1.f / sqrtf(var + 1e-5f);
  }
  __syncthreads();
  float m = mean_s, inv = inv_s;
  float* y = Y + (size_t)row * H;
  for (int j = threadIdx.x; j < H; j += 256)
    y[j] = (x[j] - m) * inv * g[j] + bta[j];
}

// ---------------- fp32 GEMM (attention path; precision-critical) ----------------
template <bool ADD>
__global__ __launch_bounds__(256) void k_gemm(const float* __restrict__ A, int lda,
                                              const void* __restrict__ W, size_t wOff, int ldw,
                                              const float* __restrict__ bias,
                                              float* __restrict__ C, int ldc,
                                              int M, int N, int K, const int* __restrict__ flag) {
  __shared__ float As[16][65];
  __shared__ float Ws[16][65];
  int f32 = *flag;
  int n0 = blockIdx.x * 64, m0 = blockIdx.y * 64;
  int tid = threadIdx.x;
  int tm = tid >> 4, tn = tid & 15;
  float acc[4][4] = {};
  for (int k0 = 0; k0 < K; k0 += 16) {
#pragma unroll
    for (int u = 0; u < 4; ++u) {
      int idx = tid + u * 256;
      int m = idx >> 4, k = idx & 15;
      int gm = m0 + m, gn = n0 + m;
      As[k][m] = (gm < M) ? A[(size_t)gm * lda + k0 + k] : 0.f;
      Ws[k][m] = (gn < N) ? ldany(W, f32, wOff + (size_t)gn * ldw + k0 + k) : 0.f;
    }
    __syncthreads();
#pragma unroll
    for (int kk = 0; kk < 16; ++kk) {
      float a[4], bb[4];
#pragma unroll
      for (int i = 0; i < 4; ++i) { a[i] = As[kk][tm * 4 + i]; bb[i] = Ws[kk][tn * 4 + i]; }
#pragma unroll
      for (int i = 0; i < 4; ++i)
#pragma unroll
        for (int j = 0; j < 4; ++j) acc[i][j] += a[i] * bb[j];
    }
    __syncthreads();
  }
#pragma unroll
  for (int i = 0; i < 4; ++i) {
    int gm = m0 + tm * 4 + i;
    if (gm >= M) continue;
#pragma unroll
    for (int j = 0; j < 4; ++j) {
      int gn = n0 + tn * 4 + j;
      if (gn >= N) continue;
      float v = acc[i][j] + bias[gn];
      size_t o = (size_t)gm * ldc + gn;
      if (ADD) v += C[o];
      C[o] = v;
    }
  }
}

// ---------------- flash-tiled attention (fp32, 64-query tile per block) ----------------
// Block = 256 threads as 16x16; each thread owns a 4x4 tile of S (64q x 64k)
// and a 4x4 tile of O (64q x 64d). Online softmax state per query row is
// replicated across the 16 'tn' lanes and reduced with shfl_xor(1,2,4,8).
// LDS: Qt[d][q] (transposed), KV (K transposed in S phase, V natural in PV phase),
// Ps[q][k]. Row stride 68 floats keeps every float4 access 16B-aligned.
__global__ __launch_bounds__(256) void k_attn_tile(const float* __restrict__ Qb, int qStride,
                                                   const float* __restrict__ Kb, int kStride,
                                                   const float* __restrict__ Vb, int vStride,
                                                   float* __restrict__ Ob, int Tq, int Tk) {
  int h = blockIdx.y, b = blockIdx.z;
  int q0 = blockIdx.x * 64;
  __shared__ float Qt[64][68];   // [d][q]
  __shared__ float KV[64][68];   // S phase: [d][k]; PV phase: [k][d]
  __shared__ float Ps[64][68];   // [q][k]
  int t = threadIdx.x;
  int tm = t >> 4, tn = t & 15;
  int sr = t >> 2, c0 = (t & 3) * 16;   // staging: row sr (0..63), 16-float chunk c0

  // stage Q transposed (once)
  {
    const float* src = Qb + ((size_t)(b * Tq + q0 + sr)) * qStride + h * HD + c0;
#pragma unroll
    for (int u = 0; u < 4; ++u) {
      f32x4 v = *(const f32x4*)(src + u * 4);
      Qt[c0 + u * 4 + 0][sr] = v.x;
      Qt[c0 + u * 4 + 1][sr] = v.y;
      Qt[c0 + u * 4 + 2][sr] = v.z;
      Qt[c0 + u * 4 + 3][sr] = v.w;
    }
  }

  float m[4], l[4];
  f32x4 oacc[4] = {};
#pragma unroll
  for (int i = 0; i < 4; ++i) { m[i] = -1e30f; l[i] = 0.f; }

  for (int k0 = 0; k0 < Tk; k0 += 64) {
    // stage K tile transposed into KV[d][k]
    {
      const float* src = Kb + ((size_t)(b * Tk + k0 + sr)) * kStride + h * HD + c0;
#pragma unroll
      for (int u = 0; u < 4; ++u) {
        f32x4 v = *(const f32x4*)(src + u * 4);
        KV[c0 + u * 4 + 0][sr] = v.x;
        KV[c0 + u * 4 + 1][sr] = v.y;
        KV[c0 + u * 4 + 2][sr] = v.z;
        KV[c0 + u * 4 + 3][sr] = v.w;
      }
    }
    __syncthreads();
    // S = Q.K^T, thread tile 4x4
    float sacc[4][4] = {};
#pragma unroll 8
    for (int d = 0; d < 64; ++d) {
      f32x4 a = *(const f32x4*)(&Qt[d][tm * 4]);
      f32x4 bb = *(const f32x4*)(&KV[d][tn * 4]);
#pragma unroll
      for (int i = 0; i < 4; ++i)
#pragma unroll
        for (int j = 0; j < 4; ++j) sacc[i][j] = fmaf(a[i], bb[j], sacc[i][j]);
    }
    __syncthreads();   // everyone done reading K from KV
    // stage V tile natural into KV[k][d]
    {
      const float* src = Vb + ((size_t)(b * Tk + k0 + sr)) * vStride + h * HD + c0;
#pragma unroll
      for (int u = 0; u < 4; ++u)
        *(f32x4*)(&KV[sr][c0 + u * 4]) = *(const f32x4*)(src + u * 4);
    }
    // online softmax in registers
#pragma unroll
    for (int i = 0; i < 4; ++i) {
      float rm = -1e30f;
#pragma unroll
      for (int j = 0; j < 4; ++j) { sacc[i][j] *= 0.125f; rm = fmaxf(rm, sacc[i][j]); }
#pragma unroll
      for (int off = 1; off < 16; off <<= 1) rm = fmaxf(rm, __shfl_xor(rm, off));
      float mnew = fmaxf(m[i], rm);
      float rs = 0.f;
#pragma unroll
      for (int j = 0; j < 4; ++j) { float p = __expf(sacc[i][j] - mnew); sacc[i][j] = p; rs += p; }
#pragma unroll
      for (int off = 1; off < 16; off <<= 1) rs += __shfl_xor(rs, off);
      float scl = __expf(m[i] - mnew);
      l[i] = l[i] * scl + rs;
      m[i] = mnew;
#pragma unroll
      for (int j = 0; j < 4; ++j) oacc[i][j] *= scl;
      f32x4 pv;
      pv.x = sacc[i][0]; pv.y = sacc[i][1]; pv.z = sacc[i][2]; pv.w = sacc[i][3];
      *(f32x4*)(&Ps[tm * 4 + i][tn * 4]) = pv;
    }
    __syncthreads();   // Ps written, V staged
    // O += P @ V
#pragma unroll 4
    for (int kk = 0; kk < 64; kk += 4) {
      f32x4 a[4];
#pragma unroll
      for (int i = 0; i < 4; ++i) a[i] = *(const f32x4*)(&Ps[tm * 4 + i][kk]);
#pragma unroll
      for (int u = 0; u < 4; ++u) {
        f32x4 vv = *(const f32x4*)(&KV[kk + u][tn * 4]);
#pragma unroll
        for (int i = 0; i < 4; ++i)
#pragma unroll
          for (int j = 0; j < 4; ++j) oacc[i][j] = fmaf(a[i][u], vv[j], oacc[i][j]);
      }
    }
    __syncthreads();   // done reading KV(V)/Ps before next tile restages
  }
#pragma unroll
  for (int i = 0; i < 4; ++i) {
    float inv = 1.f / l[i];
    f32x4 r;
#pragma unroll
    for (int j = 0; j < 4; ++j) r[j] = oacc[i][j] * inv;
    *(f32x4*)(Ob + ((size_t)(b * Tq + q0 + tm * 4 + i)) * H + h * HD + tn * 4) = r;
  }
}

// ---------------- means ----------------
__global__ __launch_bounds__(256) void k_mean_f32(const float* __restrict__ X, float* __restrict__ out, int S) {
  int i = blockIdx.x * 256 + threadIdx.x;
  int b = i >> 10, d = i & (H - 1);
  const float* p = X + (size_t)b * S * H + d;
  float s = 0.f;
  for (int t = 0; t < S; ++t) s += p[(size_t)t * H];
  out[i] = s / (float)S;
}
__global__ __launch_bounds__(256) void k_mean_in(const void* __restrict__ X, float* __restrict__ out,
                                                 int S, const int* __restrict__ flag) {
  int f32 = *flag;
  int i = blockIdx.x * 256 + threadIdx.x;
  int b = i >> 10, d = i & (H - 1);
  size_t base = (size_t)b * S * H + d;
  float s = 0.f;
  for (int t = 0; t < S; ++t) s += ldany(X, f32, base + (size_t)t * H);
  out[i] = s / (float)S;
}

// ---------------- gate ----------------
__global__ __launch_bounds__(256) void k_gate(const float* __restrict__ X, const float* __restrict__ ctx,
                                              const float* __restrict__ Wg, const float* __restrict__ bg,
                                              float* __restrict__ probs, int S) {
  int row = blockIdx.x;
  int b = row / S;
  const float* xr = X + (size_t)row * H;
  const float* cx = ctx + (size_t)b * H;
  float p[E] = {};
  for (int j = threadIdx.x; j < 2 * H; j += 256) {
    float xv = (j < H) ? xr[j] : cx[j - H];
#pragma unroll
    for (int e = 0; e < E; ++e) p[e] += xv * Wg[(size_t)e * 2 * H + j];
  }
#pragma unroll
  for (int e = 0; e < E; ++e)
#pragma unroll
    for (int off = 32; off; off >>= 1) p[e] += __shfl_xor(p[e], off);
  __shared__ float gl[4][E];
  int w = threadIdx.x >> 6, lane = threadIdx.x & 63;
  if (lane == 0)
#pragma unroll
    for (int e = 0; e < E; ++e) gl[w][e] = p[e];
  __syncthreads();
  if (threadIdx.x == 0) {
    float lg[E], mx = -1e30f;
    for (int e = 0; e < E; ++e) {
      lg[e] = gl[0][e] + gl[1][e] + gl[2][e] + gl[3][e] + bg[e];
      mx = fmaxf(mx, lg[e]);
    }
    float ssum = 0.f;
    for (int e = 0; e < E; ++e) { lg[e] = __expf(lg[e] - mx); ssum += lg[e]; }
    float inv = 1.f / ssum;
    for (int e = 0; e < E; ++e) probs[(size_t)row * E + e] = lg[e] * inv;
  }
}

// ---------------- top-k (NaN-safe, clamped) ----------------
__global__ __launch_bounds__(256) void k_topk(const float* __restrict__ probs, int S, int k,
                                              int* __restrict__ pairs, int* __restrict__ counts, int PB) {
  int e = blockIdx.x, b = blockIdx.y;
  __shared__ float vals[640];
  __shared__ float bv[256];
  __shared__ int bi[256];
  int tid = threadIdx.x;
  for (int j = tid; j < S; j += 256) {
    float v = probs[((size_t)b * S + j) * E + e];
    vals[j] = (v == v) ? v : -1e30f;
  }
  __syncthreads();
  for (int it = 0; it < k; ++it) {
    float best = -2e30f; int besti = 0;
    for (int j = tid; j < S; j += 256) {
      float v = vals[j];
      if (v > best || (v == best && j < besti)) { best = v; besti = j; }
    }
    bv[tid] = best; bi[tid] = besti;
    __syncthreads();
    for (int st = 128; st; st >>= 1) {
      if (tid < st) {
        if (bv[tid + st] > bv[tid] || (bv[tid + st] == bv[tid] && bi[tid + st] < bi[tid])) {
          bv[tid] = bv[tid + st]; bi[tid] = bi[tid + st];
        }
      }
      __syncthreads();
    }
    if (tid == 0) {
      int sidx = bi[0];
      if ((unsigned)sidx >= (unsigned)S) sidx = 0;
      pairs[e * PB + b * k + it] = b * S + sidx;
      atomicAdd(&counts[b * S + sidx], 1);
      vals[sidx] = -1e30f;
    }
    __syncthreads();
  }
}

// ================= MFMA MoE =================
// 64x64 tile, 4 waves each computing 32x32 via 2x2 mfma_f32_16x16x32_bf16, BK=64.
// LDS row stride 72 bf16 (144 B): conflict-free b128 frag reads + int4 staging writes.

#define MFMA_BF16 __builtin_amdgcn_mfma_f32_16x16x32_bf16

// up: Hb[e*PB+r][I] (bf16) = gelu(gather(X)[r] @ W1_e^T + b1_e)
__global__ __launch_bounds__(256) void k_moe_up_mfma(const float* __restrict__ X, int nTok,
                                                     const int* __restrict__ pairs, int PB,
                                                     const float* __restrict__ W1, const float* __restrict__ B1,
                                                     unsigned short* __restrict__ Hb) {
  int e = blockIdx.z;
  int n0 = blockIdx.x * 64, m0 = blockIdx.y * 64;
  __shared__ short As[64 * 72];
  __shared__ short Ws[64 * 72];
  __shared__ int rowIdx[64];
  int t = threadIdx.x;
  if (t < 64) {
    int r = m0 + t;
    int ri = (r < PB) ? pairs[(size_t)e * PB + r] : -1;
    if ((unsigned)ri >= (unsigned)nTok) ri = -1;
    rowIdx[t] = ri;
  }
  __syncthreads();
  int sr = t >> 2, sc = (t & 3) * 16;
  const float* Wrow = W1 + (size_t)e * I * H + (size_t)(n0 + sr) * H;
  int ri = rowIdx[sr];
  const float* Xrow = (ri >= 0) ? X + (size_t)ri * H : nullptr;
  int w = t >> 6, lane = t & 63;
  int wm = (w >> 1) * 32, wn = (w & 1) * 32;
  int frow = lane & 15, quad = lane >> 4;
  f32x4 acc[2][2] = {};
  for (int k0 = 0; k0 < H; k0 += 64) {
    // stage A (gathered fp32 -> bf16)
    {
      f32x4 f0 = {}, f1 = {}, f2 = {}, f3 = {};
      if (Xrow) {
        const f32x4* sp = (const f32x4*)(Xrow + k0 + sc);
        f0 = sp[0]; f1 = sp[1]; f2 = sp[2]; f3 = sp[3];
      }
      i32x4 lo, hi;
      lo.x = pack2(f0.x, f0.y); lo.y = pack2(f0.z, f0.w);
      lo.z = pack2(f1.x, f1.y); lo.w = pack2(f1.z, f1.w);
      hi.x = pack2(f2.x, f2.y); hi.y = pack2(f2.z, f2.w);
      hi.z = pack2(f3.x, f3.y); hi.w = pack2(f3.z, f3.w);
      *(i32x4*)(&As[sr * 72 + sc]) = lo;
      *(i32x4*)(&As[sr * 72 + sc + 8]) = hi;
    }
    // stage W (fp32 -> bf16)
    {
      const f32x4* sp = (const f32x4*)(Wrow + k0 + sc);
      f32x4 f0 = sp[0], f1 = sp[1], f2 = sp[2], f3 = sp[3];
      i32x4 lo, hi;
      lo.x = pack2(f0.x, f0.y); lo.y = pack2(f0.z, f0.w);
      lo.z = pack2(f1.x, f1.y); lo.w = pack2(f1.z, f1.w);
      hi.x = pack2(f2.x, f2.y); hi.y = pack2(f2.z, f2.w);
      hi.z = pack2(f3.x, f3.y); hi.w = pack2(f3.z, f3.w);
      *(i32x4*)(&Ws[sr * 72 + sc]) = lo;
      *(i32x4*)(&Ws[sr * 72 + sc + 8]) = hi;
    }
    __syncthreads();
#pragma unroll
    for (int ks = 0; ks < 64; ks += 32) {
      bf16x8 a0 = *(bf16x8*)(&As[(wm + frow) * 72 + ks + quad * 8]);
      bf16x8 a1 = *(bf16x8*)(&As[(wm + 16 + frow) * 72 + ks + quad * 8]);
      bf16x8 b0 = *(bf16x8*)(&Ws[(wn + frow) * 72 + ks + quad * 8]);
      bf16x8 b1 = *(bf16x8*)(&Ws[(wn + 16 + frow) * 72 + ks + quad * 8]);
      acc[0][0] = MFMA_BF16(a0, b0, acc[0][0], 0, 0, 0);
      acc[0][1] = MFMA_BF16(a0, b1, acc[0][1], 0, 0, 0);
      acc[1][0] = MFMA_BF16(a1, b0, acc[1][0], 0, 0, 0);
      acc[1][1] = MFMA_BF16(a1, b1, acc[1][1], 0, 0, 0);
    }
    __syncthreads();
  }
  const float* b1p = B1 + (size_t)e * I;
#pragma unroll
  for (int i = 0; i < 2; ++i) {
#pragma unroll
    for (int j = 0; j < 2; ++j) {
      int n = n0 + wn + j * 16 + frow;
      float bias = b1p[n];
#pragma unroll
      for (int reg = 0; reg < 4; ++reg) {
        int r = m0 + wm + i * 16 + quad * 4 + reg;
        if (r < PB) {
          float v = gelu_f(acc[i][j][reg] + bias);
          Hb[((size_t)e * PB + r) * I + n] = (unsigned short)f2bf_u(v);
        }
      }
    }
  }
}

// down: ACC[tok][H] += gather-scatter( Hb_e @ W2_e^T + b2_e )
__global__ __launch_bounds__(256) void k_moe_down_mfma(const unsigned short* __restrict__ Hb, int nTok,
                                                       const int* __restrict__ pairs, int PB,
                                                       const float* __restrict__ W2, const float* __restrict__ B2,
                                                       float* __restrict__ ACC) {
  int e = blockIdx.z;
  int n0 = blockIdx.x * 64, m0 = blockIdx.y * 64;
  __shared__ short As[64 * 72];
  __shared__ short Ws[64 * 72];
  __shared__ int tokLds[64];
  int t = threadIdx.x;
  if (t < 64) {
    int r = m0 + t;
    int tk = (r < PB) ? pairs[(size_t)e * PB + r] : 0;
    if ((unsigned)tk >= (unsigned)nTok) tk = 0;
    tokLds[t] = tk;
  }
  __syncthreads();
  int sr = t >> 2, sc = (t & 3) * 16;
  bool arow_ok = (m0 + sr) < PB;
  const unsigned short* Arow = Hb + ((size_t)e * PB + (m0 + sr)) * I;
  const float* Wrow = W2 + (size_t)e * H * I + (size_t)(n0 + sr) * I;
  int w = t >> 6, lane = t & 63;
  int wm = (w >> 1) * 32, wn = (w & 1) * 32;
  int frow = lane & 15, quad = lane >> 4;
  f32x4 acc[2][2] = {};
  for (int k0 = 0; k0 < I; k0 += 64) {
    // stage A (bf16 direct copy)
    {
      i32x4 lo = {}, hi = {};
      if (arow_ok) {
        const i32x4* sp = (const i32x4*)(Arow + k0 + sc);
        lo = sp[0]; hi = sp[1];
      }
      *(i32x4*)(&As[sr * 72 + sc]) = lo;
      *(i32x4*)(&As[sr * 72 + sc + 8]) = hi;
    }
    // stage W (fp32 -> bf16)
    {
      const f32x4* sp = (const f32x4*)(Wrow + k0 + sc);
      f32x4 f0 = sp[0], f1 = sp[1], f2 = sp[2], f3 = sp[3];
      i32x4 lo, hi;
      lo.x = pack2(f0.x, f0.y); lo.y = pack2(f0.z, f0.w);
      lo.z = pack2(f1.x, f1.y); lo.w = pack2(f1.z, f1.w);
      hi.x = pack2(f2.x, f2.y); hi.y = pack2(f2.z, f2.w);
      hi.z = pack2(f3.x, f3.y); hi.w = pack2(f3.z, f3.w);
      *(i32x4*)(&Ws[sr * 72 + sc]) = lo;
      *(i32x4*)(&Ws[sr * 72 + sc + 8]) = hi;
    }
    __syncthreads();
#pragma unroll
    for (int ks = 0; ks < 64; ks += 32) {
      bf16x8 a0 = *(bf16x8*)(&As[(wm + frow) * 72 + ks + quad * 8]);
      bf16x8 a1 = *(bf16x8*)(&As[(wm + 16 + frow) * 72 + ks + quad * 8]);
      bf16x8 b0 = *(bf16x8*)(&Ws[(wn + frow) * 72 + ks + quad * 8]);
      bf16x8 b1 = *(bf16x8*)(&Ws[(wn + 16 + frow) * 72 + ks + quad * 8]);
      acc[0][0] = MFMA_BF16(a0, b0, acc[0][0], 0, 0, 0);
      acc[0][1] = MFMA_BF16(a0, b1, acc[0][1], 0, 0, 0);
      acc[1][0] = MFMA_BF16(a1, b0, acc[1][0], 0, 0, 0);
      acc[1][1] = MFMA_BF16(a1, b1, acc[1][1], 0, 0, 0);
    }
    __syncthreads();
  }
  const float* b2p = B2 + (size_t)e * H;
#pragma unroll
  for (int i = 0; i < 2; ++i) {
#pragma unroll
    for (int j = 0; j < 2; ++j) {
      int n = n0 + wn + j * 16 + frow;
      float bias = b2p[n];
#pragma unroll
      for (int reg = 0; reg < 4; ++reg) {
        int r = m0 + wm + i * 16 + quad * 4 + reg;
        if (r < PB) {
          int tok = tokLds[wm + i * 16 + quad * 4 + reg];
          atomicAdd(&ACC[(size_t)tok * H + n], acc[i][j][reg] + bias);
        }
      }
    }
  }
}

// ---------------- final ----------------
__global__ __launch_bounds__(256) void k_final(const float* __restrict__ base, const float* __restrict__ acc,
                                               const int* __restrict__ cnt, float* __restrict__ out, int n) {
  int i = blockIdx.x * 256 + threadIdx.x;
  if (i >= n) return;
  int row = i >> 10;
  int c = cnt[row]; if (c < 1) c = 1;
  out[i] = base[i] + acc[i] / (float)c;
}

extern "C" void kernel_launch(void* const* d_in, const int* in_sizes, int n_in,
                              void* d_out, int out_size, void* d_ws, size_t ws_size,
                              hipStream_t stream) {
  float* out = (float*)d_out;
  dim3 blk(256);
  const int OUT_N = (int)(FQ + FIMG);
  int outN = out_size;

  static const int EXP[25] = {
    B * T * H, B * V * H, B * L * H,
    3 * H * H, 3 * H, H * H, H,
    3 * H * H, 3 * H, H * H, H,
    E * 2 * H, E, E * 2 * H, E,
    E * I * H, E * I, E * H * I, E * H,
    H, H, H, H, H, H
  };
  if (n_in != 25) { k_diag<<<dim3((outN + 255) / 256), blk, 0, stream>>>(out, outN, 40000.f); return; }
  for (int i = 0; i < 25; ++i)
    if (in_sizes[i] != EXP[i]) {
      k_diag<<<dim3((outN + 255) / 256), blk, 0, stream>>>(out, outN, 20000.f + 1000.f * i);
      return;
    }
  if (out_size != OUT_N) { k_diag<<<dim3((outN + 255) / 256), blk, 0, stream>>>(out, outN, 30000.f); return; }
  if (ws_size < WS_FLOATS * sizeof(float)) {
    k_diag<<<dim3((outN + 255) / 256), blk, 0, stream>>>(out, outN, 12345.f);
    return;
  }

  float* wsf = (float*)d_ws;
  float* Q = wsf + oQ;  float* XN = wsf + oXN;  float* AO = wsf + oAO;  float* IMG32 = wsf + oIMG;
  float* CTXI = wsf + oCTXI;  float* CTXT = wsf + oCTXT;
  float* PRT = wsf + oPRT;    float* PRI = wsf + oPRI;
  float* SW = wsf + oSW;
  int* FLAG = (int*)(wsf + oINT);
  int* PAIRS_T = FLAG + 1;
  int* PAIRS_I = PAIRS_T + E * PBT;
  int* CNT_T = PAIRS_I + E * PBI;
  int* CNT_I = CNT_T + B * T;
  float* QKV = wsf + oBIG;                       // attention phase
  unsigned short* HBu = (unsigned short*)(wsf + oBIG);  // MoE phase (QKV dead)

  k_detect<<<dim3(1), blk, 0, stream>>>(d_in[0], FLAG);

  struct CV { int idx; size_t off; int n; };
  const CV cvs[16] = {
    {4, sSA_B_IN, 3 * H}, {6, sSA_B_OUT, H}, {8, sCA_B_IN, 3 * H}, {10, sCA_B_OUT, H},
    {11, sGIW, E * 2 * H}, {12, sGIB, E}, {13, sGTW, E * 2 * H}, {14, sGTB, E},
    {16, sEB1, E * I}, {18, sEB2, E * H},
    {19, sLNQG, H}, {20, sLNQB, H}, {21, sLNCG, H}, {22, sLNCB, H}, {23, sLNFG, H}, {24, sLNFB, H}
  };
  for (int c = 0; c < 16; ++c)
    k_cvt2<<<dim3((cvs[c].n + 255) / 256), blk, 0, stream>>>(d_in[cvs[c].idx], SW + cvs[c].off, cvs[c].n, FLAG);

  k_cvt2<<<dim3((int)(FQ / 256)), blk, 0, stream>>>(d_in[0], Q, (int)FQ, FLAG);
  k_cvt2<<<dim3((int)(FIMG / 256)), blk, 0, stream>>>(d_in[1], IMG32, (int)FIMG, FLAG);

  // ---- 1) self-attention ----
  k_ln<<<dim3(B * T), blk, 0, stream>>>(Q, SW + sLNQG, SW + sLNQB, XN);
  k_gemm<false><<<dim3(3 * H / 64, B * T / 64), blk, 0, stream>>>(
      XN, H, d_in[3], 0, H, SW + sSA_B_IN, QKV, 3 * H, B * T, 3 * H, H, FLAG);
  k_attn_tile<<<dim3(T / 64, NH, B), blk, 0, stream>>>(QKV, 3 * H, QKV + H, 3 * H, QKV + 2 * H, 3 * H, AO, T, T);
  k_gemm<true><<<dim3(H / 64, B * T / 64), blk, 0, stream>>>(
      AO, H, d_in[5], 0, H, SW + sSA_B_OUT, Q, H, B * T, H, H, FLAG);

  // ---- 2) cross-attention ----
  k_ln<<<dim3(B * T), blk, 0, stream>>>(Q, SW + sLNCG, SW + sLNCB, XN);
  k_gemm<false><<<dim3(H / 64, B * T / 64), blk, 0, stream>>>(
      XN, H, d_in[7], 0, H, SW + sCA_B_IN, QKV, H, B * T, H, H, FLAG);
  k_gemm<false><<<dim3(2 * H / 64, B * V / 64), blk, 0, stream>>>(
      IMG32, H, d_in[7], (size_t)H * H, H, SW + sCA_B_IN + H, QKV + FQ, 2 * H, B * V, 2 * H, H, FLAG);
  k_attn_tile<<<dim3(T / 64, NH, B), blk, 0, stream>>>(QKV, H, QKV + FQ, 2 * H, QKV + FQ + H, 2 * H, AO, T, V);
  k_gemm<true><<<dim3(H / 64, B * T / 64), blk, 0, stream>>>(
      AO, H, d_in[9], 0, H, SW + sCA_B_OUT, Q, H, B * T, H, H, FLAG);

  // ---- 3) gating ----
  k_mean_f32<<<dim3((B * H) / 256), blk, 0, stream>>>(IMG32, CTXI, V);
  k_mean_in<<<dim3((B * H) / 256), blk, 0, stream>>>(d_in[2], CTXT, L, FLAG);
  k_gate<<<dim3(B * T), blk, 0, stream>>>(Q, CTXI, SW + sGTW, SW + sGTB, PRT, T);
  k_gate<<<dim3(B * V), blk, 0, stream>>>(IMG32, CTXT, SW + sGIW, SW + sGIB, PRI, V);
  k_zeroi<<<dim3((B * T + B * V + 255) / 256), blk, 0, stream>>>(CNT_T, B * T + B * V);

  // ---- 4) text MoE (MFMA) ----
  k_topk<<<dim3(E, B), blk, 0, stream>>>(PRT, T, KT, PAIRS_T, CNT_T, PBT);
  k_ln<<<dim3(B * T), blk, 0, stream>>>(Q, SW + sLNFG, SW + sLNFB, XN);
  k_zerof<<<dim3((int)(FQ / 256)), blk, 0, stream>>>(AO, (int)FQ);
  k_moe_up_mfma<<<dim3(I / 64, PBT / 64, E), blk, 0, stream>>>(
      XN, B * T, PAIRS_T, PBT, (const float*)d_in[15], (const float*)d_in[16], HBu);
  k_moe_down_mfma<<<dim3(H / 64, PBT / 64, E), blk, 0, stream>>>(
      HBu, B * T, PAIRS_T, PBT, (const float*)d_in[17], (const float*)d_in[18], AO);
  k_final<<<dim3((int)(FQ / 256)), blk, 0, stream>>>(Q, AO, CNT_T, out, (int)FQ);

  // ---- 5) image MoE (MFMA) ----
  k_topk<<<dim3(E, B), blk, 0, stream>>>(PRI, V, KI, PAIRS_I, CNT_I, PBI);
  k_zerof<<<dim3((int)(FIMG / 256)), blk, 0, stream>>>(AO, (int)FIMG);
  k_moe_up_mfma<<<dim3(I / 64, (PBI + 63) / 64, E), blk, 0, stream>>>(
      IMG32, B * V, PAIRS_I, PBI, (const float*)d_in[15], (const float*)d_in[16], HBu);
  k_moe_down_mfma<<<dim3(H / 64, (PBI + 63) / 64, E), blk, 0, stream>>>(
      HBu, B * V, PAIRS_I, PBI, (const float*)d_in[17], (const float*)d_in[18], AO);
  k_final<<<dim3((int)(FIMG / 256)), blk, 0, stream>>>(IMG32, AO, CNT_I, out + FQ, (int)FIMG);
}

// Round 2
// 2187.546 us; speedup vs baseline: 1.7135x; 1.1910x over previous
//
#include <hip/hip_runtime.h>
#include <hip/hip_bf16.h>

using bf16 = __hip_bfloat16;

namespace {
constexpr int B = 4, T = 512, V = 576, L = 256, H = 1024, NH = 16, HD = 64, I = 4096, E = 8;
constexpr int KT = 80;          // int(1.25*512 + 7) // 8 = 80
constexpr int KI = 90;          // int(1.25*576 + 7) // 8 = 90
constexpr int PBT = B * KT;     // 320
constexpr int PBI = B * KI;     // 360

constexpr size_t FQ   = (size_t)B * T * H;   // 2,097,152
constexpr size_t FIMG = (size_t)B * V * H;   // 2,359,296
constexpr size_t FQKV = FQ + (size_t)B * V * 2 * H;  // 6,815,744
constexpr size_t FHB  = (size_t)E * PBI * I;         // 11,796,480 (bf16 elems in MoE phase)

// small-weight (fp32-converted) region offsets
constexpr size_t sSA_B_IN = 0, sSA_B_OUT = 3072, sCA_B_IN = 4096, sCA_B_OUT = 7168;
constexpr size_t sGIW = 8192, sGIB = 24576, sGTW = 24584, sGTB = 40968;
constexpr size_t sEB1 = 40976, sEB2 = 73744;
constexpr size_t sLNQG = 81936, sLNQB = 82960, sLNCG = 83984, sLNCB = 85008, sLNFG = 86032, sLNFB = 87056;
constexpr size_t SWN = 88080;

// ws layout (float offsets)
constexpr size_t oQ = 0, oXN = oQ + FQ, oAO = oXN + FQ, oIMG = oAO + FIMG;
constexpr size_t oCTXI = oIMG + FIMG, oCTXT = oCTXI + (size_t)B * H;
constexpr size_t oPRT = oCTXT + (size_t)B * H, oPRI = oPRT + (size_t)B * T * E;
constexpr size_t oSW = oPRI + (size_t)B * V * E;
constexpr size_t oINT = oSW + SWN;                      // int region (flag + pairs + counts)
constexpr size_t oBIG = oINT + 16384;                   // QKV(f32) / HB(bf16) union
constexpr size_t WS_FLOATS = oBIG + (FQKV > FHB ? FQKV : FHB);
}

typedef __attribute__((ext_vector_type(8))) short bf16x8;
typedef __attribute__((ext_vector_type(4))) float f32x4;
typedef __attribute__((ext_vector_type(4))) int i32x4;

__device__ __forceinline__ float b2f(bf16 x) { return __bfloat162float(x); }

__device__ __forceinline__ float ldany(const void* p, int f32, size_t idx) {
  return f32 ? ((const float*)p)[idx] : b2f(((const bf16*)p)[idx]);
}

__device__ __forceinline__ unsigned int f2bf_u(float v) {   // RNE fp32->bf16 bits
  unsigned int u = __float_as_uint(v);
  u += 0x7FFFu + ((u >> 16) & 1u);
  return u >> 16;
}
__device__ __forceinline__ int pack2(float a, float b) {
  return (int)(f2bf_u(a) | (f2bf_u(b) << 16));
}

__device__ __forceinline__ float gelu_f(float x) {
  float x3 = x * x * x;
  return 0.5f * x * (1.f + tanhf(0.7978845608028654f * (x + 0.044715f * x3)));
}

// ---------------- dtype probe ----------------
__global__ __launch_bounds__(256) void k_detect(const void* __restrict__ q, int* __restrict__ flag) {
  __shared__ int cnt;
  if (threadIdx.x == 0) cnt = 0;
  __syncthreads();
  int local = 0;
  for (int i = threadIdx.x; i < 65536; i += 256) {
    float v = b2f(((const bf16*)q)[i]);
    if (!(fabsf(v) < 1e4f)) local++;
  }
  atomicAdd(&cnt, local);
  __syncthreads();
  if (threadIdx.x == 0) *flag = (cnt > 64) ? 1 : 0;
}

__global__ __launch_bounds__(256) void k_cvt2(const void* __restrict__ in, float* __restrict__ out,
                                              int n, const int* __restrict__ flag) {
  int f32 = *flag;
  int i = blockIdx.x * 256 + threadIdx.x;
  if (i < n) out[i] = ldany(in, f32, (size_t)i);
}

__global__ __launch_bounds__(256) void k_zerof(float* __restrict__ p, int n) {
  int i = blockIdx.x * 256 + threadIdx.x;
  if (i < n) p[i] = 0.f;
}
__global__ __launch_bounds__(256) void k_zeroi(int* __restrict__ p, int n) {
  int i = blockIdx.x * 256 + threadIdx.x;
  if (i < n) p[i] = 0;
}
__global__ __launch_bounds__(256) void k_diag(float* __restrict__ out, int n, float code) {
  int i = blockIdx.x * 256 + threadIdx.x;
  if (i < n) out[i] = (i == 0 ? code : 0.f);
}

// ---------------- LayerNorm ----------------
__global__ __launch_bounds__(256) void k_ln(const float* __restrict__ X,
                                            const float* __restrict__ g, const float* __restrict__ bta,
                                            float* __restrict__ Y) {
  int row = blockIdx.x;
  const float* x = X + (size_t)row * H;
  float s = 0.f, ss = 0.f;
  for (int j = threadIdx.x; j < H; j += 256) { float v = x[j]; s += v; ss += v * v; }
#pragma unroll
  for (int off = 32; off; off >>= 1) { s += __shfl_xor(s, off); ss += __shfl_xor(ss, off); }
  __shared__ float ls[4], lss[4];
  __shared__ float mean_s, inv_s;
  int w = threadIdx.x >> 6, lane = threadIdx.x & 63;
  if (lane == 0) { ls[w] = s; lss[w] = ss; }
  __syncthreads();
  if (threadIdx.x == 0) {
    float S1 = ls[0] + ls[1] + ls[2] + ls[3];
    float S2 = lss[0] + lss[1] + lss[2] + lss[3];
    float m = S1 / (float)H;
    float var = S2 / (float)H - m * m;
    mean_s = m;
    inv_s = 1.f / sqrtf(var + 1e-5f);
  }
  __syncthreads();
  float m = mean_s, inv = inv_s;
  float* y = Y + (size_t)row * H;
  for (int j = threadIdx.x; j < H; j += 256)
    y[j] = (x[j] - m) * inv * g[j] + bta[j];
}

// ---------------- fp32 GEMM (attention path; precision-critical) ----------------
// BM x BN tile, K-step 32, 256 threads as 16x16, per-thread (BM/64 x BN/64) grid of
// 4x4 float4 microtiles. LDS K-major at stride BM+4 / BN+4 floats: every fragment
// read is a 16B-aligned ds_read_b128 with only broadcast/2-way bank aliasing.
// All call-site dims divide the tile sizes exactly (no guards).
template <int BM, int BN, bool ADD>
__global__ __launch_bounds__(256) void k_gemm(const float* __restrict__ A, int lda,
                                              const void* __restrict__ W, size_t wOff, int ldw,
                                              const float* __restrict__ bias,
                                              float* __restrict__ C, int ldc,
                                              int M, int N, int K, const int* __restrict__ flag) {
  constexpr int RI = BM / 64, RJ = BN / 64;
  constexpr int TPR_A = 256 / BM, CPT_A = 32 / TPR_A;   // threads per A row, floats per thread
  constexpr int TPR_B = 256 / BN, CPT_B = 32 / TPR_B;
  __shared__ float As[32][BM + 4];
  __shared__ float Ws[32][BN + 4];
  int f32 = *flag;
  int n0 = blockIdx.x * BN, m0 = blockIdx.y * BM;
  int t = threadIdx.x;
  int tm = t >> 4, tn = t & 15;
  int arow = t / TPR_A, ac0 = (t % TPR_A) * CPT_A;
  int brow = t / TPR_B, bc0 = (t % TPR_B) * CPT_B;
  const float* Ap = A + (size_t)(m0 + arow) * lda + ac0;
  float acc[RI][RJ][4][4] = {};
  for (int k0 = 0; k0 < K; k0 += 32) {
    // stage A (fp32 workspace, transposed into K-major)
    {
      const f32x4* sp = (const f32x4*)(Ap + k0);
#pragma unroll
      for (int u = 0; u < CPT_A / 4; ++u) {
        f32x4 v = sp[u];
        As[ac0 + u * 4 + 0][arow] = v.x;
        As[ac0 + u * 4 + 1][arow] = v.y;
        As[ac0 + u * 4 + 2][arow] = v.z;
        As[ac0 + u * 4 + 3][arow] = v.w;
      }
    }
    // stage W (raw input, fp32 fast path / bf16 fallback)
    if (f32) {
      const float* Wp = (const float*)W + wOff + (size_t)(n0 + brow) * ldw + bc0 + k0;
      const f32x4* sp = (const f32x4*)Wp;
#pragma unroll
      for (int u = 0; u < CPT_B / 4; ++u) {
        f32x4 v = sp[u];
        Ws[bc0 + u * 4 + 0][brow] = v.x;
        Ws[bc0 + u * 4 + 1][brow] = v.y;
        Ws[bc0 + u * 4 + 2][brow] = v.z;
        Ws[bc0 + u * 4 + 3][brow] = v.w;
      }
    } else {
      const bf16* Wp = (const bf16*)W + wOff + (size_t)(n0 + brow) * ldw + bc0 + k0;
#pragma unroll
      for (int u = 0; u < CPT_B; ++u) Ws[bc0 + u][brow] = b2f(Wp[u]);
    }
    __syncthreads();
#pragma unroll 8
    for (int kk = 0; kk < 32; ++kk) {
      f32x4 a[RI], bb[RJ];
#pragma unroll
      for (int ri = 0; ri < RI; ++ri) a[ri] = *(const f32x4*)(&As[kk][ri * 64 + tm * 4]);
#pragma unroll
      for (int rj = 0; rj < RJ; ++rj) bb[rj] = *(const f32x4*)(&Ws[kk][rj * 64 + tn * 4]);
#pragma unroll
      for (int ri = 0; ri < RI; ++ri)
#pragma unroll
        for (int rj = 0; rj < RJ; ++rj)
#pragma unroll
          for (int i = 0; i < 4; ++i)
#pragma unroll
            for (int j = 0; j < 4; ++j)
              acc[ri][rj][i][j] = fmaf(a[ri][i], bb[rj][j], acc[ri][rj][i][j]);
    }
    __syncthreads();
  }
#pragma unroll
  for (int ri = 0; ri < RI; ++ri)
#pragma unroll
    for (int i = 0; i < 4; ++i) {
      int gm = m0 + ri * 64 + tm * 4 + i;
      float* crow = C + (size_t)gm * ldc + n0;
#pragma unroll
      for (int rj = 0; rj < RJ; ++rj) {
        int cn = rj * 64 + tn * 4;
        f32x4 bv = *(const f32x4*)(bias + n0 + cn);
        f32x4 r;
#pragma unroll
        for (int j = 0; j < 4; ++j) r[j] = acc[ri][rj][i][j] + bv[j];
        if (ADD) r += *(const f32x4*)(crow + cn);
        *(f32x4*)(crow + cn) = r;
      }
    }
}

// ---------------- flash-tiled attention (fp32, 64-query tile per block) ----------------
__global__ __launch_bounds__(256) void k_attn_tile(const float* __restrict__ Qb, int qStride,
                                                   const float* __restrict__ Kb, int kStride,
                                                   const float* __restrict__ Vb, int vStride,
                                                   float* __restrict__ Ob, int Tq, int Tk) {
  int h = blockIdx.y, b = blockIdx.z;
  int q0 = blockIdx.x * 64;
  __shared__ float Qt[64][68];   // [d][q]
  __shared__ float KV[64][68];   // S phase: [d][k]; PV phase: [k][d]
  __shared__ float Ps[64][68];   // [q][k]
  int t = threadIdx.x;
  int tm = t >> 4, tn = t & 15;
  int sr = t >> 2, c0 = (t & 3) * 16;   // staging: row sr (0..63), 16-float chunk c0

  // stage Q transposed (once)
  {
    const float* src = Qb + ((size_t)(b * Tq + q0 + sr)) * qStride + h * HD + c0;
#pragma unroll
    for (int u = 0; u < 4; ++u) {
      f32x4 v = *(const f32x4*)(src + u * 4);
      Qt[c0 + u * 4 + 0][sr] = v.x;
      Qt[c0 + u * 4 + 1][sr] = v.y;
      Qt[c0 + u * 4 + 2][sr] = v.z;
      Qt[c0 + u * 4 + 3][sr] = v.w;
    }
  }

  float m[4], l[4];
  f32x4 oacc[4] = {};
#pragma unroll
  for (int i = 0; i < 4; ++i) { m[i] = -1e30f; l[i] = 0.f; }

  for (int k0 = 0; k0 < Tk; k0 += 64) {
    // stage K tile transposed into KV[d][k]
    {
      const float* src = Kb + ((size_t)(b * Tk + k0 + sr)) * kStride + h * HD + c0;
#pragma unroll
      for (int u = 0; u < 4; ++u) {
        f32x4 v = *(const f32x4*)(src + u * 4);
        KV[c0 + u * 4 + 0][sr] = v.x;
        KV[c0 + u * 4 + 1][sr] = v.y;
        KV[c0 + u * 4 + 2][sr] = v.z;
        KV[c0 + u * 4 + 3][sr] = v.w;
      }
    }
    __syncthreads();
    // S = Q.K^T, thread tile 4x4
    float sacc[4][4] = {};
#pragma unroll 8
    for (int d = 0; d < 64; ++d) {
      f32x4 a = *(const f32x4*)(&Qt[d][tm * 4]);
      f32x4 bb = *(const f32x4*)(&KV[d][tn * 4]);
#pragma unroll
      for (int i = 0; i < 4; ++i)
#pragma unroll
        for (int j = 0; j < 4; ++j) sacc[i][j] = fmaf(a[i], bb[j], sacc[i][j]);
    }
    __syncthreads();   // everyone done reading K from KV
    // stage V tile natural into KV[k][d]
    {
      const float* src = Vb + ((size_t)(b * Tk + k0 + sr)) * vStride + h * HD + c0;
#pragma unroll
      for (int u = 0; u < 4; ++u)
        *(f32x4*)(&KV[sr][c0 + u * 4]) = *(const f32x4*)(src + u * 4);
    }
    // online softmax in registers
#pragma unroll
    for (int i = 0; i < 4; ++i) {
      float rm = -1e30f;
#pragma unroll
      for (int j = 0; j < 4; ++j) { sacc[i][j] *= 0.125f; rm = fmaxf(rm, sacc[i][j]); }
#pragma unroll
      for (int off = 1; off < 16; off <<= 1) rm = fmaxf(rm, __shfl_xor(rm, off));
      float mnew = fmaxf(m[i], rm);
      float rs = 0.f;
#pragma unroll
      for (int j = 0; j < 4; ++j) { float p = __expf(sacc[i][j] - mnew); sacc[i][j] = p; rs += p; }
#pragma unroll
      for (int off = 1; off < 16; off <<= 1) rs += __shfl_xor(rs, off);
      float scl = __expf(m[i] - mnew);
      l[i] = l[i] * scl + rs;
      m[i] = mnew;
#pragma unroll
      for (int j = 0; j < 4; ++j) oacc[i][j] *= scl;
      f32x4 pv;
      pv.x = sacc[i][0]; pv.y = sacc[i][1]; pv.z = sacc[i][2]; pv.w = sacc[i][3];
      *(f32x4*)(&Ps[tm * 4 + i][tn * 4]) = pv;
    }
    __syncthreads();   // Ps written, V staged
    // O += P @ V
#pragma unroll 4
    for (int kk = 0; kk < 64; kk += 4) {
      f32x4 a[4];
#pragma unroll
      for (int i = 0; i < 4; ++i) a[i] = *(const f32x4*)(&Ps[tm * 4 + i][kk]);
#pragma unroll
      for (int u = 0; u < 4; ++u) {
        f32x4 vv = *(const f32x4*)(&KV[kk + u][tn * 4]);
#pragma unroll
        for (int i = 0; i < 4; ++i)
#pragma unroll
          for (int j = 0; j < 4; ++j) oacc[i][j] = fmaf(a[i][u], vv[j], oacc[i][j]);
      }
    }
    __syncthreads();   // done reading KV(V)/Ps before next tile restages
  }
#pragma unroll
  for (int i = 0; i < 4; ++i) {
    float inv = 1.f / l[i];
    f32x4 r;
#pragma unroll
    for (int j = 0; j < 4; ++j) r[j] = oacc[i][j] * inv;
    *(f32x4*)(Ob + ((size_t)(b * Tq + q0 + tm * 4 + i)) * H + h * HD + tn * 4) = r;
  }
}

// ---------------- means ----------------
__global__ __launch_bounds__(256) void k_mean_f32(const float* __restrict__ X, float* __restrict__ out, int S) {
  int i = blockIdx.x * 256 + threadIdx.x;
  int b = i >> 10, d = i & (H - 1);
  const float* p = X + (size_t)b * S * H + d;
  float s = 0.f;
  for (int t = 0; t < S; ++t) s += p[(size_t)t * H];
  out[i] = s / (float)S;
}
__global__ __launch_bounds__(256) void k_mean_in(const void* __restrict__ X, float* __restrict__ out,
                                                 int S, const int* __restrict__ flag) {
  int f32 = *flag;
  int i = blockIdx.x * 256 + threadIdx.x;
  int b = i >> 10, d = i & (H - 1);
  size_t base = (size_t)b * S * H + d;
  float s = 0.f;
  for (int t = 0; t < S; ++t) s += ldany(X, f32, base + (size_t)t * H);
  out[i] = s / (float)S;
}

// ---------------- gate ----------------
__global__ __launch_bounds__(256) void k_gate(const float* __restrict__ X, const float* __restrict__ ctx,
                                              const float* __restrict__ Wg, const float* __restrict__ bg,
                                              float* __restrict__ probs, int S) {
  int row = blockIdx.x;
  int b = row / S;
  const float* xr = X + (size_t)row * H;
  const float* cx = ctx + (size_t)b * H;
  float p[E] = {};
  for (int j = threadIdx.x; j < 2 * H; j += 256) {
    float xv = (j < H) ? xr[j] : cx[j - H];
#pragma unroll
    for (int e = 0; e < E; ++e) p[e] += xv * Wg[(size_t)e * 2 * H + j];
  }
#pragma unroll
  for (int e = 0; e < E; ++e)
#pragma unroll
    for (int off = 32; off; off >>= 1) p[e] += __shfl_xor(p[e], off);
  __shared__ float gl[4][E];
  int w = threadIdx.x >> 6, lane = threadIdx.x & 63;
  if (lane == 0)
#pragma unroll
    for (int e = 0; e < E; ++e) gl[w][e] = p[e];
  __syncthreads();
  if (threadIdx.x == 0) {
    float lg[E], mx = -1e30f;
    for (int e = 0; e < E; ++e) {
      lg[e] = gl[0][e] + gl[1][e] + gl[2][e] + gl[3][e] + bg[e];
      mx = fmaxf(mx, lg[e]);
    }
    float ssum = 0.f;
    for (int e = 0; e < E; ++e) { lg[e] = __expf(lg[e] - mx); ssum += lg[e]; }
    float inv = 1.f / ssum;
    for (int e = 0; e < E; ++e) probs[(size_t)row * E + e] = lg[e] * inv;
  }
}

// ---------------- top-k (NaN-safe, clamped) ----------------
__global__ __launch_bounds__(256) void k_topk(const float* __restrict__ probs, int S, int k,
                                              int* __restrict__ pairs, int* __restrict__ counts, int PB) {
  int e = blockIdx.x, b = blockIdx.y;
  __shared__ float vals[640];
  __shared__ float bv[256];
  __shared__ int bi[256];
  int tid = threadIdx.x;
  for (int j = tid; j < S; j += 256) {
    float v = probs[((size_t)b * S + j) * E + e];
    vals[j] = (v == v) ? v : -1e30f;
  }
  __syncthreads();
  for (int it = 0; it < k; ++it) {
    float best = -2e30f; int besti = 0;
    for (int j = tid; j < S; j += 256) {
      float v = vals[j];
      if (v > best || (v == best && j < besti)) { best = v; besti = j; }
    }
    bv[tid] = best; bi[tid] = besti;
    __syncthreads();
    for (int st = 128; st; st >>= 1) {
      if (tid < st) {
        if (bv[tid + st] > bv[tid] || (bv[tid + st] == bv[tid] && bi[tid + st] < bi[tid])) {
          bv[tid] = bv[tid + st]; bi[tid] = bi[tid + st];
        }
      }
      __syncthreads();
    }
    if (tid == 0) {
      int sidx = bi[0];
      if ((unsigned)sidx >= (unsigned)S) sidx = 0;
      pairs[e * PB + b * k + it] = b * S + sidx;
      atomicAdd(&counts[b * S + sidx], 1);
      vals[sidx] = -1e30f;
    }
    __syncthreads();
  }
}

// ================= MFMA MoE =================
// 64x64 tile, 4 waves each computing 32x32 via 2x2 mfma_f32_16x16x32_bf16, BK=64.
// LDS row stride 72 bf16 (144 B): conflict-free b128 frag reads + int4 staging writes.

#define MFMA_BF16 __builtin_amdgcn_mfma_f32_16x16x32_bf16

// up: Hb[e*PB+r][I] (bf16) = gelu(gather(X)[r] @ W1_e^T + b1_e)
__global__ __launch_bounds__(256) void k_moe_up_mfma(const float* __restrict__ X, int nTok,
                                                     const int* __restrict__ pairs, int PB,
                                                     const float* __restrict__ W1, const float* __restrict__ B1,
                                                     unsigned short* __restrict__ Hb) {
  int e = blockIdx.z;
  int n0 = blockIdx.x * 64, m0 = blockIdx.y * 64;
  __shared__ short As[64 * 72];
  __shared__ short Ws[64 * 72];
  __shared__ int rowIdx[64];
  int t = threadIdx.x;
  if (t < 64) {
    int r = m0 + t;
    int ri = (r < PB) ? pairs[(size_t)e * PB + r] : -1;
    if ((unsigned)ri >= (unsigned)nTok) ri = -1;
    rowIdx[t] = ri;
  }
  __syncthreads();
  int sr = t >> 2, sc = (t & 3) * 16;
  const float* Wrow = W1 + (size_t)e * I * H + (size_t)(n0 + sr) * H;
  int ri = rowIdx[sr];
  const float* Xrow = (ri >= 0) ? X + (size_t)ri * H : nullptr;
  int w = t >> 6, lane = t & 63;
  int wm = (w >> 1) * 32, wn = (w & 1) * 32;
  int frow = lane & 15, quad = lane >> 4;
  f32x4 acc[2][2] = {};
  for (int k0 = 0; k0 < H; k0 += 64) {
    // stage A (gathered fp32 -> bf16)
    {
      f32x4 f0 = {}, f1 = {}, f2 = {}, f3 = {};
      if (Xrow) {
        const f32x4* sp = (const f32x4*)(Xrow + k0 + sc);
        f0 = sp[0]; f1 = sp[1]; f2 = sp[2]; f3 = sp[3];
      }
      i32x4 lo, hi;
      lo.x = pack2(f0.x, f0.y); lo.y = pack2(f0.z, f0.w);
      lo.z = pack2(f1.x, f1.y); lo.w = pack2(f1.z, f1.w);
      hi.x = pack2(f2.x, f2.y); hi.y = pack2(f2.z, f2.w);
      hi.z = pack2(f3.x, f3.y); hi.w = pack2(f3.z, f3.w);
      *(i32x4*)(&As[sr * 72 + sc]) = lo;
      *(i32x4*)(&As[sr * 72 + sc + 8]) = hi;
    }
    // stage W (fp32 -> bf16)
    {
      const f32x4* sp = (const f32x4*)(Wrow + k0 + sc);
      f32x4 f0 = sp[0], f1 = sp[1], f2 = sp[2], f3 = sp[3];
      i32x4 lo, hi;
      lo.x = pack2(f0.x, f0.y); lo.y = pack2(f0.z, f0.w);
      lo.z = pack2(f1.x, f1.y); lo.w = pack2(f1.z, f1.w);
      hi.x = pack2(f2.x, f2.y); hi.y = pack2(f2.z, f2.w);
      hi.z = pack2(f3.x, f3.y); hi.w = pack2(f3.z, f3.w);
      *(i32x4*)(&Ws[sr * 72 + sc]) = lo;
      *(i32x4*)(&Ws[sr * 72 + sc + 8]) = hi;
    }
    __syncthreads();
#pragma unroll
    for (int ks = 0; ks < 64; ks += 32) {
      bf16x8 a0 = *(bf16x8*)(&As[(wm + frow) * 72 + ks + quad * 8]);
      bf16x8 a1 = *(bf16x8*)(&As[(wm + 16 + frow) * 72 + ks + quad * 8]);
      bf16x8 b0 = *(bf16x8*)(&Ws[(wn + frow) * 72 + ks + quad * 8]);
      bf16x8 b1 = *(bf16x8*)(&Ws[(wn + 16 + frow) * 72 + ks + quad * 8]);
      acc[0][0] = MFMA_BF16(a0, b0, acc[0][0], 0, 0, 0);
      acc[0][1] = MFMA_BF16(a0, b1, acc[0][1], 0, 0, 0);
      acc[1][0] = MFMA_BF16(a1, b0, acc[1][0], 0, 0, 0);
      acc[1][1] = MFMA_BF16(a1, b1, acc[1][1], 0, 0, 0);
    }
    __syncthreads();
  }
  const float* b1p = B1 + (size_t)e * I;
#pragma unroll
  for (int i = 0; i < 2; ++i) {
#pragma unroll
    for (int j = 0; j < 2; ++j) {
      int n = n0 + wn + j * 16 + frow;
      float bias = b1p[n];
#pragma unroll
      for (int reg = 0; reg < 4; ++reg) {
        int r = m0 + wm + i * 16 + quad * 4 + reg;
        if (r < PB) {
          float v = gelu_f(acc[i][j][reg] + bias);
          Hb[((size_t)e * PB + r) * I + n] = (unsigned short)f2bf_u(v);
        }
      }
    }
  }
}

// down: ACC[tok][H] += gather-scatter( Hb_e @ W2_e^T + b2_e )
__global__ __launch_bounds__(256) void k_moe_down_mfma(const unsigned short* __restrict__ Hb, int nTok,
                                                       const int* __restrict__ pairs, int PB,
                                                       const float* __restrict__ W2, const float* __restrict__ B2,
                                                       float* __restrict__ ACC) {
  int e = blockIdx.z;
  int n0 = blockIdx.x * 64, m0 = blockIdx.y * 64;
  __shared__ short As[64 * 72];
  __shared__ short Ws[64 * 72];
  __shared__ int tokLds[64];
  int t = threadIdx.x;
  if (t < 64) {
    int r = m0 + t;
    int tk = (r < PB) ? pairs[(size_t)e * PB + r] : 0;
    if ((unsigned)tk >= (unsigned)nTok) tk = 0;
    tokLds[t] = tk;
  }
  __syncthreads();
  int sr = t >> 2, sc = (t & 3) * 16;
  bool arow_ok = (m0 + sr) < PB;
  const unsigned short* Arow = Hb + ((size_t)e * PB + (m0 + sr)) * I;
  const float* Wrow = W2 + (size_t)e * H * I + (size_t)(n0 + sr) * I;
  int w = t >> 6, lane = t & 63;
  int wm = (w >> 1) * 32, wn = (w & 1) * 32;
  int frow = lane & 15, quad = lane >> 4;
  f32x4 acc[2][2] = {};
  for (int k0 = 0; k0 < I; k0 += 64) {
    // stage A (bf16 direct copy)
    {
      i32x4 lo = {}, hi = {};
      if (arow_ok) {
        const i32x4* sp = (const i32x4*)(Arow + k0 + sc);
        lo = sp[0]; hi = sp[1];
      }
      *(i32x4*)(&As[sr * 72 + sc]) = lo;
      *(i32x4*)(&As[sr * 72 + sc + 8]) = hi;
    }
    // stage W (fp32 -> bf16)
    {
      const f32x4* sp = (const f32x4*)(Wrow + k0 + sc);
      f32x4 f0 = sp[0], f1 = sp[1], f2 = sp[2], f3 = sp[3];
      i32x4 lo, hi;
      lo.x = pack2(f0.x, f0.y); lo.y = pack2(f0.z, f0.w);
      lo.z = pack2(f1.x, f1.y); lo.w = pack2(f1.z, f1.w);
      hi.x = pack2(f2.x, f2.y); hi.y = pack2(f2.z, f2.w);
      hi.z = pack2(f3.x, f3.y); hi.w = pack2(f3.z, f3.w);
      *(i32x4*)(&Ws[sr * 72 + sc]) = lo;
      *(i32x4*)(&Ws[sr * 72 + sc + 8]) = hi;
    }
    __syncthreads();
#pragma unroll
    for (int ks = 0; ks < 64; ks += 32) {
      bf16x8 a0 = *(bf16x8*)(&As[(wm + frow) * 72 + ks + quad * 8]);
      bf16x8 a1 = *(bf16x8*)(&As[(wm + 16 + frow) * 72 + ks + quad * 8]);
      bf16x8 b0 = *(bf16x8*)(&Ws[(wn + frow) * 72 + ks + quad * 8]);
      bf16x8 b1 = *(bf16x8*)(&Ws[(wn + 16 + frow) * 72 + ks + quad * 8]);
      acc[0][0] = MFMA_BF16(a0, b0, acc[0][0], 0, 0, 0);
      acc[0][1] = MFMA_BF16(a0, b1, acc[0][1], 0, 0, 0);
      acc[1][0] = MFMA_BF16(a1, b0, acc[1][0], 0, 0, 0);
      acc[1][1] = MFMA_BF16(a1, b1, acc[1][1], 0, 0, 0);
    }
    __syncthreads();
  }
  const float* b2p = B2 + (size_t)e * H;
#pragma unroll
  for (int i = 0; i < 2; ++i) {
#pragma unroll
    for (int j = 0; j < 2; ++j) {
      int n = n0 + wn + j * 16 + frow;
      float bias = b2p[n];
#pragma unroll
      for (int reg = 0; reg < 4; ++reg) {
        int r = m0 + wm + i * 16 + quad * 4 + reg;
        if (r < PB) {
          int tok = tokLds[wm + i * 16 + quad * 4 + reg];
          atomicAdd(&ACC[(size_t)tok * H + n], acc[i][j][reg] + bias);
        }
      }
    }
  }
}

// ---------------- final ----------------
__global__ __launch_bounds__(256) void k_final(const float* __restrict__ base, const float* __restrict__ acc,
                                               const int* __restrict__ cnt, float* __restrict__ out, int n) {
  int i = blockIdx.x * 256 + threadIdx.x;
  if (i >= n) return;
  int row = i >> 10;
  int c = cnt[row]; if (c < 1) c = 1;
  out[i] = base[i] + acc[i] / (float)c;
}

extern "C" void kernel_launch(void* const* d_in, const int* in_sizes, int n_in,
                              void* d_out, int out_size, void* d_ws, size_t ws_size,
                              hipStream_t stream) {
  float* out = (float*)d_out;
  dim3 blk(256);
  const int OUT_N = (int)(FQ + FIMG);
  int outN = out_size;

  static const int EXP[25] = {
    B * T * H, B * V * H, B * L * H,
    3 * H * H, 3 * H, H * H, H,
    3 * H * H, 3 * H, H * H, H,
    E * 2 * H, E, E * 2 * H, E,
    E * I * H, E * I, E * H * I, E * H,
    H, H, H, H, H, H
  };
  if (n_in != 25) { k_diag<<<dim3((outN + 255) / 256), blk, 0, stream>>>(out, outN, 40000.f); return; }
  for (int i = 0; i < 25; ++i)
    if (in_sizes[i] != EXP[i]) {
      k_diag<<<dim3((outN + 255) / 256), blk, 0, stream>>>(out, outN, 20000.f + 1000.f * i);
      return;
    }
  if (out_size != OUT_N) { k_diag<<<dim3((outN + 255) / 256), blk, 0, stream>>>(out, outN, 30000.f); return; }
  if (ws_size < WS_FLOATS * sizeof(float)) {
    k_diag<<<dim3((outN + 255) / 256), blk, 0, stream>>>(out, outN, 12345.f);
    return;
  }

  float* wsf = (float*)d_ws;
  float* Q = wsf + oQ;  float* XN = wsf + oXN;  float* AO = wsf + oAO;  float* IMG32 = wsf + oIMG;
  float* CTXI = wsf + oCTXI;  float* CTXT = wsf + oCTXT;
  float* PRT = wsf + oPRT;    float* PRI = wsf + oPRI;
  float* SW = wsf + oSW;
  int* FLAG = (int*)(wsf + oINT);
  int* PAIRS_T = FLAG + 1;
  int* PAIRS_I = PAIRS_T + E * PBT;
  int* CNT_T = PAIRS_I + E * PBI;
  int* CNT_I = CNT_T + B * T;
  float* QKV = wsf + oBIG;                       // attention phase
  unsigned short* HBu = (unsigned short*)(wsf + oBIG);  // MoE phase (QKV dead)

  k_detect<<<dim3(1), blk, 0, stream>>>(d_in[0], FLAG);

  struct CV { int idx; size_t off; int n; };
  const CV cvs[16] = {
    {4, sSA_B_IN, 3 * H}, {6, sSA_B_OUT, H}, {8, sCA_B_IN, 3 * H}, {10, sCA_B_OUT, H},
    {11, sGIW, E * 2 * H}, {12, sGIB, E}, {13, sGTW, E * 2 * H}, {14, sGTB, E},
    {16, sEB1, E * I}, {18, sEB2, E * H},
    {19, sLNQG, H}, {20, sLNQB, H}, {21, sLNCG, H}, {22, sLNCB, H}, {23, sLNFG, H}, {24, sLNFB, H}
  };
  for (int c = 0; c < 16; ++c)
    k_cvt2<<<dim3((cvs[c].n + 255) / 256), blk, 0, stream>>>(d_in[cvs[c].idx], SW + cvs[c].off, cvs[c].n, FLAG);

  k_cvt2<<<dim3((int)(FQ / 256)), blk, 0, stream>>>(d_in[0], Q, (int)FQ, FLAG);
  k_cvt2<<<dim3((int)(FIMG / 256)), blk, 0, stream>>>(d_in[1], IMG32, (int)FIMG, FLAG);

  // ---- 1) self-attention ----
  k_ln<<<dim3(B * T), blk, 0, stream>>>(Q, SW + sLNQG, SW + sLNQB, XN);
  k_gemm<128, 128, false><<<dim3(3 * H / 128, B * T / 128), blk, 0, stream>>>(
      XN, H, d_in[3], 0, H, SW + sSA_B_IN, QKV, 3 * H, B * T, 3 * H, H, FLAG);
  k_attn_tile<<<dim3(T / 64, NH, B), blk, 0, stream>>>(QKV, 3 * H, QKV + H, 3 * H, QKV + 2 * H, 3 * H, AO, T, T);
  k_gemm<128, 64, true><<<dim3(H / 64, B * T / 128), blk, 0, stream>>>(
      AO, H, d_in[5], 0, H, SW + sSA_B_OUT, Q, H, B * T, H, H, FLAG);

  // ---- 2) cross-attention ----
  k_ln<<<dim3(B * T), blk, 0, stream>>>(Q, SW + sLNCG, SW + sLNCB, XN);
  k_gemm<128, 64, false><<<dim3(H / 64, B * T / 128), blk, 0, stream>>>(
      XN, H, d_in[7], 0, H, SW + sCA_B_IN, QKV, H, B * T, H, H, FLAG);
  k_gemm<128, 128, false><<<dim3(2 * H / 128, B * V / 128), blk, 0, stream>>>(
      IMG32, H, d_in[7], (size_t)H * H, H, SW + sCA_B_IN + H, QKV + FQ, 2 * H, B * V, 2 * H, H, FLAG);
  k_attn_tile<<<dim3(T / 64, NH, B), blk, 0, stream>>>(QKV, H, QKV + FQ, 2 * H, QKV + FQ + H, 2 * H, AO, T, V);
  k_gemm<128, 64, true><<<dim3(H / 64, B * T / 128), blk, 0, stream>>>(
      AO, H, d_in[9], 0, H, SW + sCA_B_OUT, Q, H, B * T, H, H, FLAG);

  // ---- 3) gating ----
  k_mean_f32<<<dim3((B * H) / 256), blk, 0, stream>>>(IMG32, CTXI, V);
  k_mean_in<<<dim3((B * H) / 256), blk, 0, stream>>>(d_in[2], CTXT, L, FLAG);
  k_gate<<<dim3(B * T), blk, 0, stream>>>(Q, CTXI, SW + sGTW, SW + sGTB, PRT, T);
  k_gate<<<dim3(B * V), blk, 0, stream>>>(IMG32, CTXT, SW + sGIW, SW + sGIB, PRI, V);
  k_zeroi<<<dim3((B * T + B * V + 255) / 256), blk, 0, stream>>>(CNT_T, B * T + B * V);

  // ---- 4) text MoE (MFMA) ----
  k_topk<<<dim3(E, B), blk, 0, stream>>>(PRT, T, KT, PAIRS_T, CNT_T, PBT);
  k_ln<<<dim3(B * T), blk, 0, stream>>>(Q, SW + sLNFG, SW + sLNFB, XN);
  k_zerof<<<dim3((int)(FQ / 256)), blk, 0, stream>>>(AO, (int)FQ);
  k_moe_up_mfma<<<dim3(I / 64, PBT / 64, E), blk, 0, stream>>>(
      XN, B * T, PAIRS_T, PBT, (const float*)d_in[15], (const float*)d_in[16], HBu);
  k_moe_down_mfma<<<dim3(H / 64, PBT / 64, E), blk, 0, stream>>>(
      HBu, B * T, PAIRS_T, PBT, (const float*)d_in[17], (const float*)d_in[18], AO);
  k_final<<<dim3((int)(FQ / 256)), blk, 0, stream>>>(Q, AO, CNT_T, out, (int)FQ);

  // ---- 5) image MoE (MFMA) ----
  k_topk<<<dim3(E, B), blk, 0, stream>>>(PRI, V, KI, PAIRS_I, CNT_I, PBI);
  k_zerof<<<dim3((int)(FIMG / 256)), blk, 0, stream>>>(AO, (int)FIMG);
  k_moe_up_mfma<<<dim3(I / 64, (PBI + 63) / 64, E), blk, 0, stream>>>(
      IMG32, B * V, PAIRS_I, PBI, (const float*)d_in[15], (const float*)d_in[16], HBu);
  k_moe_down_mfma<<<dim3(H / 64, (PBI + 63) / 64, E), blk, 0, stream>>>(
      HBu, B * V, PAIRS_I, PBI, (const float*)d_in[17], (const float*)d_in[18], AO);
  k_final<<<dim3((int)(FIMG / 256)), blk, 0, stream>>>(IMG32, AO, CNT_I, out + FQ, (int)FIMG);
}

// Round 3
// 2025.633 us; speedup vs baseline: 1.8505x; 1.0799x over previous
//
#include <hip/hip_runtime.h>
#include <hip/hip_bf16.h>

using bf16 = __hip_bfloat16;

namespace {
constexpr int B = 4, T = 512, V = 576, L = 256, H = 1024, NH = 16, HD = 64, I = 4096, E = 8;
constexpr int KT = 80;          // int(1.25*512 + 7) // 8 = 80
constexpr int KI = 90;          // int(1.25*576 + 7) // 8 = 90
constexpr int PBT = B * KT;     // 320
constexpr int PBI = B * KI;     // 360

constexpr size_t FQ   = (size_t)B * T * H;   // 2,097,152
constexpr size_t FIMG = (size_t)B * V * H;   // 2,359,296
constexpr size_t FQKV = FQ + (size_t)B * V * 2 * H;  // 6,815,744
constexpr size_t FHB  = (size_t)E * PBI * I;         // 11,796,480 (bf16 elems in MoE phase)

// small-weight (fp32-converted) region offsets (prefix-contiguous)
constexpr size_t sSA_B_IN = 0, sSA_B_OUT = 3072, sCA_B_IN = 4096, sCA_B_OUT = 7168;
constexpr size_t sGIW = 8192, sGIB = 24576, sGTW = 24584, sGTB = 40968;
constexpr size_t sEB1 = 40976, sEB2 = 73744;
constexpr size_t sLNQG = 81936, sLNQB = 82960, sLNCG = 83984, sLNCB = 85008, sLNFG = 86032, sLNFB = 87056;
constexpr size_t SWN = 88080;

// ws layout (float offsets)
constexpr size_t oQ = 0, oXN = oQ + FQ, oAO = oXN + FQ, oIMG = oAO + FIMG;
constexpr size_t oCTXI = oIMG + FIMG, oCTXT = oCTXI + (size_t)B * H;
constexpr size_t oPRT = oCTXT + (size_t)B * H, oPRI = oPRT + (size_t)B * T * E;
constexpr size_t oSW = oPRI + (size_t)B * V * E;
constexpr size_t oINT = oSW + SWN;                      // int region (flag + pairs + counts)
constexpr size_t oBIG = oINT + 16384;                   // QKV(f32) / HB(bf16) union
constexpr size_t WS_FLOATS = oBIG + (FQKV > FHB ? FQKV : FHB);
}

typedef __attribute__((ext_vector_type(8))) short bf16x8;
typedef __attribute__((ext_vector_type(4))) float f32x4;
typedef __attribute__((ext_vector_type(4))) int i32x4;

__device__ __forceinline__ float b2f(bf16 x) { return __bfloat162float(x); }

__device__ __forceinline__ float ldany(const void* p, int f32, size_t idx) {
  return f32 ? ((const float*)p)[idx] : b2f(((const bf16*)p)[idx]);
}

__device__ __forceinline__ unsigned int f2bf_u(float v) {   // RNE fp32->bf16 bits
  unsigned int u = __float_as_uint(v);
  u += 0x7FFFu + ((u >> 16) & 1u);
  return u >> 16;
}
__device__ __forceinline__ int pack2(float a, float b) {
  return (int)(f2bf_u(a) | (f2bf_u(b) << 16));
}

__device__ __forceinline__ float gelu_f(float x) {
  float x3 = x * x * x;
  return 0.5f * x * (1.f + tanhf(0.7978845608028654f * (x + 0.044715f * x3)));
}

// ---------------- dtype probe ----------------
__global__ __launch_bounds__(256) void k_detect(const void* __restrict__ q, int* __restrict__ flag) {
  __shared__ int cnt;
  if (threadIdx.x == 0) cnt = 0;
  __syncthreads();
  int local = 0;
  for (int i = threadIdx.x; i < 65536; i += 256) {
    float v = b2f(((const bf16*)q)[i]);
    if (!(fabsf(v) < 1e4f)) local++;
  }
  atomicAdd(&cnt, local);
  __syncthreads();
  if (threadIdx.x == 0) *flag = (cnt > 64) ? 1 : 0;
}

__global__ __launch_bounds__(256) void k_cvt2(const void* __restrict__ in, float* __restrict__ out,
                                              int n, const int* __restrict__ flag) {
  int f32 = *flag;
  int i = blockIdx.x * 256 + threadIdx.x;
  if (i < n) out[i] = ldany(in, f32, (size_t)i);
}

// fused 16-segment small-weight conversion (segments are prefix-contiguous in dst)
struct CvtTab { const void* src[16]; int start[17]; };
__global__ __launch_bounds__(256) void k_cvt_multi(CvtTab tab, float* __restrict__ out,
                                                   const int* __restrict__ flag) {
  int f32 = *flag;
  int i = blockIdx.x * 256 + threadIdx.x;
  if (i >= (int)SWN) return;
  int lo = 0, hi = 15;
  while (lo < hi) { int mid = (lo + hi + 1) >> 1; if (i >= tab.start[mid]) lo = mid; else hi = mid - 1; }
  out[i] = ldany(tab.src[lo], f32, (size_t)(i - tab.start[lo]));
}

__global__ __launch_bounds__(256) void k_zerof(float* __restrict__ p, int n) {
  int i = blockIdx.x * 256 + threadIdx.x;
  if (i < n) p[i] = 0.f;
}
__global__ __launch_bounds__(256) void k_zeroi(int* __restrict__ p, int n) {
  int i = blockIdx.x * 256 + threadIdx.x;
  if (i < n) p[i] = 0;
}
__global__ __launch_bounds__(256) void k_diag(float* __restrict__ out, int n, float code) {
  int i = blockIdx.x * 256 + threadIdx.x;
  if (i < n) out[i] = (i == 0 ? code : 0.f);
}

// ---------------- LayerNorm ----------------
__global__ __launch_bounds__(256) void k_ln(const float* __restrict__ X,
                                            const float* __restrict__ g, const float* __restrict__ bta,
                                            float* __restrict__ Y) {
  int row = blockIdx.x;
  const float* x = X + (size_t)row * H;
  float s = 0.f, ss = 0.f;
  for (int j = threadIdx.x; j < H; j += 256) { float v = x[j]; s += v; ss += v * v; }
#pragma unroll
  for (int off = 32; off; off >>= 1) { s += __shfl_xor(s, off); ss += __shfl_xor(ss, off); }
  __shared__ float ls[4], lss[4];
  __shared__ float mean_s, inv_s;
  int w = threadIdx.x >> 6, lane = threadIdx.x & 63;
  if (lane == 0) { ls[w] = s; lss[w] = ss; }
  __syncthreads();
  if (threadIdx.x == 0) {
    float S1 = ls[0] + ls[1] + ls[2] + ls[3];
    float S2 = lss[0] + lss[1] + lss[2] + lss[3];
    float m = S1 / (float)H;
    float var = S2 / (float)H - m * m;
    mean_s = m;
    inv_s = 1.f / sqrtf(var + 1e-5f);
  }
  __syncthreads();
  float m = mean_s, inv = inv_s;
  float* y = Y + (size_t)row * H;
  for (int j = threadIdx.x; j < H; j += 256)
    y[j] = (x[j] - m) * inv * g[j] + bta[j];
}

// ---------------- fp32 GEMM (attention path; precision-critical) ----------------
// BM x BN tile, K-step 32, 256 threads as 16x16, software-prefetched global staging:
// K-tile k+1 is loaded into registers right after the barrier, hiding HBM/L2 latency
// under the 32-step FMA loop. LDS K-major at stride BM+4 / BN+4: fragment reads are
// 16B-aligned ds_read_b128. All call-site dims divide tile sizes exactly.
template <int BM, int BN, bool ADD>
__global__ __launch_bounds__(256) void k_gemm(const float* __restrict__ A, int lda,
                                              const void* __restrict__ W, size_t wOff, int ldw,
                                              const float* __restrict__ bias,
                                              float* __restrict__ C, int ldc,
                                              int M, int N, int K, const int* __restrict__ flag) {
  constexpr int RI = BM / 64, RJ = BN / 64;
  constexpr int TPR_A = 256 / BM, CPT_A = 32 / TPR_A;   // threads per A row, floats per thread
  constexpr int TPR_B = 256 / BN, CPT_B = 32 / TPR_B;
  __shared__ float As[32][BM + 4];
  __shared__ float Ws[32][BN + 4];
  int f32 = *flag;
  int n0 = blockIdx.x * BN, m0 = blockIdx.y * BM;
  int t = threadIdx.x;
  int tm = t >> 4, tn = t & 15;
  int arow = t / TPR_A, ac0 = (t % TPR_A) * CPT_A;
  int brow = t / TPR_B, bc0 = (t % TPR_B) * CPT_B;
  const float* ApK = A + (size_t)(m0 + arow) * lda + ac0;
  const float* WpF = (const float*)W + wOff + (size_t)(n0 + brow) * ldw + bc0;
  const bf16*  WpH = (const bf16*)W + wOff + (size_t)(n0 + brow) * ldw + bc0;

  f32x4 pa[CPT_A / 4];
  f32x4 pwf[CPT_B / 4];
  i32x4 pwh[(CPT_B + 7) / 8];

  auto fetch = [&](int k0) {
#pragma unroll
    for (int u = 0; u < CPT_A / 4; ++u) pa[u] = *(const f32x4*)(ApK + k0 + u * 4);
    if (f32) {
#pragma unroll
      for (int u = 0; u < CPT_B / 4; ++u) pwf[u] = *(const f32x4*)(WpF + k0 + u * 4);
    } else {
#pragma unroll
      for (int u = 0; u < (CPT_B + 7) / 8; ++u) pwh[u] = *(const i32x4*)(WpH + k0 + u * 8);
    }
  };
  auto store_lds = [&]() {
#pragma unroll
    for (int u = 0; u < CPT_A / 4; ++u) {
      f32x4 v = pa[u];
      As[ac0 + u * 4 + 0][arow] = v.x;
      As[ac0 + u * 4 + 1][arow] = v.y;
      As[ac0 + u * 4 + 2][arow] = v.z;
      As[ac0 + u * 4 + 3][arow] = v.w;
    }
    if (f32) {
#pragma unroll
      for (int u = 0; u < CPT_B / 4; ++u) {
        f32x4 v = pwf[u];
        Ws[bc0 + u * 4 + 0][brow] = v.x;
        Ws[bc0 + u * 4 + 1][brow] = v.y;
        Ws[bc0 + u * 4 + 2][brow] = v.z;
        Ws[bc0 + u * 4 + 3][brow] = v.w;
      }
    } else {
#pragma unroll
      for (int u = 0; u < (CPT_B + 7) / 8; ++u) {
        i32x4 v = pwh[u];
#pragma unroll
        for (int q = 0; q < 4; ++q) {
          unsigned int uu = (unsigned int)v[q];
          Ws[bc0 + u * 8 + q * 2 + 0][brow] = __uint_as_float((uu & 0xFFFFu) << 16);
          Ws[bc0 + u * 8 + q * 2 + 1][brow] = __uint_as_float((uu >> 16) << 16);
        }
      }
    }
  };

  float acc[RI][RJ][4][4] = {};
  fetch(0);
  for (int k0 = 0; k0 < K; k0 += 32) {
    store_lds();
    __syncthreads();
    if (k0 + 32 < K) fetch(k0 + 32);
#pragma unroll 8
    for (int kk = 0; kk < 32; ++kk) {
      f32x4 a[RI], bb[RJ];
#pragma unroll
      for (int ri = 0; ri < RI; ++ri) a[ri] = *(const f32x4*)(&As[kk][ri * 64 + tm * 4]);
#pragma unroll
      for (int rj = 0; rj < RJ; ++rj) bb[rj] = *(const f32x4*)(&Ws[kk][rj * 64 + tn * 4]);
#pragma unroll
      for (int ri = 0; ri < RI; ++ri)
#pragma unroll
        for (int rj = 0; rj < RJ; ++rj)
#pragma unroll
          for (int i = 0; i < 4; ++i)
#pragma unroll
            for (int j = 0; j < 4; ++j)
              acc[ri][rj][i][j] = fmaf(a[ri][i], bb[rj][j], acc[ri][rj][i][j]);
    }
    __syncthreads();
  }
#pragma unroll
  for (int ri = 0; ri < RI; ++ri)
#pragma unroll
    for (int i = 0; i < 4; ++i) {
      int gm = m0 + ri * 64 + tm * 4 + i;
      float* crow = C + (size_t)gm * ldc + n0;
#pragma unroll
      for (int rj = 0; rj < RJ; ++rj) {
        int cn = rj * 64 + tn * 4;
        f32x4 bv = *(const f32x4*)(bias + n0 + cn);
        f32x4 r;
#pragma unroll
        for (int j = 0; j < 4; ++j) r[j] = acc[ri][rj][i][j] + bv[j];
        if (ADD) r += *(const f32x4*)(crow + cn);
        *(f32x4*)(crow + cn) = r;
      }
    }
}

// ---------------- flash-tiled attention (fp32, 64-query tile per block) ----------------
__global__ __launch_bounds__(256) void k_attn_tile(const float* __restrict__ Qb, int qStride,
                                                   const float* __restrict__ Kb, int kStride,
                                                   const float* __restrict__ Vb, int vStride,
                                                   float* __restrict__ Ob, int Tq, int Tk) {
  int h = blockIdx.y, b = blockIdx.z;
  int q0 = blockIdx.x * 64;
  __shared__ float Qt[64][68];   // [d][q]
  __shared__ float KV[64][68];   // S phase: [d][k]; PV phase: [k][d]
  __shared__ float Ps[64][68];   // [q][k]
  int t = threadIdx.x;
  int tm = t >> 4, tn = t & 15;
  int sr = t >> 2, c0 = (t & 3) * 16;   // staging: row sr (0..63), 16-float chunk c0

  // stage Q transposed (once)
  {
    const float* src = Qb + ((size_t)(b * Tq + q0 + sr)) * qStride + h * HD + c0;
#pragma unroll
    for (int u = 0; u < 4; ++u) {
      f32x4 v = *(const f32x4*)(src + u * 4);
      Qt[c0 + u * 4 + 0][sr] = v.x;
      Qt[c0 + u * 4 + 1][sr] = v.y;
      Qt[c0 + u * 4 + 2][sr] = v.z;
      Qt[c0 + u * 4 + 3][sr] = v.w;
    }
  }

  float m[4], l[4];
  f32x4 oacc[4] = {};
#pragma unroll
  for (int i = 0; i < 4; ++i) { m[i] = -1e30f; l[i] = 0.f; }

  for (int k0 = 0; k0 < Tk; k0 += 64) {
    // stage K tile transposed into KV[d][k]
    {
      const float* src = Kb + ((size_t)(b * Tk + k0 + sr)) * kStride + h * HD + c0;
#pragma unroll
      for (int u = 0; u < 4; ++u) {
        f32x4 v = *(const f32x4*)(src + u * 4);
        KV[c0 + u * 4 + 0][sr] = v.x;
        KV[c0 + u * 4 + 1][sr] = v.y;
        KV[c0 + u * 4 + 2][sr] = v.z;
        KV[c0 + u * 4 + 3][sr] = v.w;
      }
    }
    __syncthreads();
    // S = Q.K^T, thread tile 4x4
    float sacc[4][4] = {};
#pragma unroll 8
    for (int d = 0; d < 64; ++d) {
      f32x4 a = *(const f32x4*)(&Qt[d][tm * 4]);
      f32x4 bb = *(const f32x4*)(&KV[d][tn * 4]);
#pragma unroll
      for (int i = 0; i < 4; ++i)
#pragma unroll
        for (int j = 0; j < 4; ++j) sacc[i][j] = fmaf(a[i], bb[j], sacc[i][j]);
    }
    __syncthreads();   // everyone done reading K from KV
    // stage V tile natural into KV[k][d]
    {
      const float* src = Vb + ((size_t)(b * Tk + k0 + sr)) * vStride + h * HD + c0;
#pragma unroll
      for (int u = 0; u < 4; ++u)
        *(f32x4*)(&KV[sr][c0 + u * 4]) = *(const f32x4*)(src + u * 4);
    }
    // online softmax in registers
#pragma unroll
    for (int i = 0; i < 4; ++i) {
      float rm = -1e30f;
#pragma unroll
      for (int j = 0; j < 4; ++j) { sacc[i][j] *= 0.125f; rm = fmaxf(rm, sacc[i][j]); }
#pragma unroll
      for (int off = 1; off < 16; off <<= 1) rm = fmaxf(rm, __shfl_xor(rm, off));
      float mnew = fmaxf(m[i], rm);
      float rs = 0.f;
#pragma unroll
      for (int j = 0; j < 4; ++j) { float p = __expf(sacc[i][j] - mnew); sacc[i][j] = p; rs += p; }
#pragma unroll
      for (int off = 1; off < 16; off <<= 1) rs += __shfl_xor(rs, off);
      float scl = __expf(m[i] - mnew);
      l[i] = l[i] * scl + rs;
      m[i] = mnew;
#pragma unroll
      for (int j = 0; j < 4; ++j) oacc[i][j] *= scl;
      f32x4 pv;
      pv.x = sacc[i][0]; pv.y = sacc[i][1]; pv.z = sacc[i][2]; pv.w = sacc[i][3];
      *(f32x4*)(&Ps[tm * 4 + i][tn * 4]) = pv;
    }
    __syncthreads();   // Ps written, V staged
    // O += P @ V
#pragma unroll 4
    for (int kk = 0; kk < 64; kk += 4) {
      f32x4 a[4];
#pragma unroll
      for (int i = 0; i < 4; ++i) a[i] = *(const f32x4*)(&Ps[tm * 4 + i][kk]);
#pragma unroll
      for (int u = 0; u < 4; ++u) {
        f32x4 vv = *(const f32x4*)(&KV[kk + u][tn * 4]);
#pragma unroll
        for (int i = 0; i < 4; ++i)
#pragma unroll
          for (int j = 0; j < 4; ++j) oacc[i][j] = fmaf(a[i][u], vv[j], oacc[i][j]);
      }
    }
    __syncthreads();   // done reading KV(V)/Ps before next tile restages
  }
#pragma unroll
  for (int i = 0; i < 4; ++i) {
    float inv = 1.f / l[i];
    f32x4 r;
#pragma unroll
    for (int j = 0; j < 4; ++j) r[j] = oacc[i][j] * inv;
    *(f32x4*)(Ob + ((size_t)(b * Tq + q0 + tm * 4 + i)) * H + h * HD + tn * 4) = r;
  }
}

// ---------------- means ----------------
__global__ __launch_bounds__(256) void k_mean_f32(const float* __restrict__ X, float* __restrict__ out, int S) {
  int i = blockIdx.x * 256 + threadIdx.x;
  int b = i >> 10, d = i & (H - 1);
  const float* p = X + (size_t)b * S * H + d;
  float s = 0.f;
  for (int t = 0; t < S; ++t) s += p[(size_t)t * H];
  out[i] = s / (float)S;
}
__global__ __launch_bounds__(256) void k_mean_in(const void* __restrict__ X, float* __restrict__ out,
                                                 int S, const int* __restrict__ flag) {
  int f32 = *flag;
  int i = blockIdx.x * 256 + threadIdx.x;
  int b = i >> 10, d = i & (H - 1);
  size_t base = (size_t)b * S * H + d;
  float s = 0.f;
  for (int t = 0; t < S; ++t) s += ldany(X, f32, base + (size_t)t * H);
  out[i] = s / (float)S;
}

// ---------------- gate ----------------
__global__ __launch_bounds__(256) void k_gate(const float* __restrict__ X, const float* __restrict__ ctx,
                                              const float* __restrict__ Wg, const float* __restrict__ bg,
                                              float* __restrict__ probs, int S) {
  int row = blockIdx.x;
  int b = row / S;
  const float* xr = X + (size_t)row * H;
  const float* cx = ctx + (size_t)b * H;
  float p[E] = {};
  for (int j = threadIdx.x; j < 2 * H; j += 256) {
    float xv = (j < H) ? xr[j] : cx[j - H];
#pragma unroll
    for (int e = 0; e < E; ++e) p[e] += xv * Wg[(size_t)e * 2 * H + j];
  }
#pragma unroll
  for (int e = 0; e < E; ++e)
#pragma unroll
    for (int off = 32; off; off >>= 1) p[e] += __shfl_xor(p[e], off);
  __shared__ float gl[4][E];
  int w = threadIdx.x >> 6, lane = threadIdx.x & 63;
  if (lane == 0)
#pragma unroll
    for (int e = 0; e < E; ++e) gl[w][e] = p[e];
  __syncthreads();
  if (threadIdx.x == 0) {
    float lg[E], mx = -1e30f;
    for (int e = 0; e < E; ++e) {
      lg[e] = gl[0][e] + gl[1][e] + gl[2][e] + gl[3][e] + bg[e];
      mx = fmaxf(mx, lg[e]);
    }
    float ssum = 0.f;
    for (int e = 0; e < E; ++e) { lg[e] = __expf(lg[e] - mx); ssum += lg[e]; }
    float inv = 1.f / ssum;
    for (int e = 0; e < E; ++e) probs[(size_t)row * E + e] = lg[e] * inv;
  }
}

// ---------------- fused wave-parallel top-k (both streams, barrier-free) ----------------
// One wave per (expert, batch) pair; 4 waves/block; 64 pairs total (text + image).
// Same selection + tie rule as jax.lax.top_k path: larger value wins, then lower index.
__global__ __launch_bounds__(256) void k_topk2(const float* __restrict__ probsT, const float* __restrict__ probsI,
                                               int* __restrict__ pairsT, int* __restrict__ pairsI,
                                               int* __restrict__ cntT, int* __restrict__ cntI) {
  __shared__ float vals[4][640];
  int wv = threadIdx.x >> 6, lane = threadIdx.x & 63;
  int p = blockIdx.x * 4 + wv;             // 0..63
  int st = p >> 5, idx = p & 31;
  int e = idx >> 2, b = idx & 3;
  const float* probs = st ? probsI : probsT;
  int S  = st ? V : T;
  int k  = st ? KI : KT;
  int* pairs = st ? pairsI : pairsT;
  int* cnt   = st ? cntI : cntT;
  int PB = st ? PBI : PBT;
  float* v = vals[wv];
  for (int j = lane; j < S; j += 64) {
    float x = probs[((size_t)b * S + j) * E + e];
    v[j] = (x == x) ? x : -1e30f;
  }
  // wave-private region: no cross-wave sharing, wave executes in lockstep -> no barriers
  for (int it = 0; it < k; ++it) {
    float best = -2e30f; int besti = 0x7FFFFFFF;
    for (int j = lane; j < S; j += 64) {
      float x = v[j];
      if (x > best || (x == best && j < besti)) { best = x; besti = j; }
    }
#pragma unroll
    for (int off = 1; off < 64; off <<= 1) {
      float ob = __shfl_xor(best, off);
      int   oi = __shfl_xor(besti, off);
      if (ob > best || (ob == best && oi < besti)) { best = ob; besti = oi; }
    }
    int sidx = besti;
    if ((unsigned)sidx >= (unsigned)S) sidx = 0;
    if (lane == 0) {
      pairs[e * PB + b * k + it] = b * S + sidx;
      atomicAdd(&cnt[b * S + sidx], 1);
    }
    v[sidx] = -1e30f;   // all lanes, same addr, same value
  }
}

// ================= MFMA MoE =================
// 64x64 tile, 4 waves each computing 32x32 via 2x2 mfma_f32_16x16x32_bf16, BK=64.
// LDS row stride 72 bf16 (144 B): conflict-free b128 frag reads + int4 staging writes.

#define MFMA_BF16 __builtin_amdgcn_mfma_f32_16x16x32_bf16

// up: Hb[e*PB+r][I] (bf16) = gelu(gather(X)[r] @ W1_e^T + b1_e)
__global__ __launch_bounds__(256) void k_moe_up_mfma(const float* __restrict__ X, int nTok,
                                                     const int* __restrict__ pairs, int PB,
                                                     const float* __restrict__ W1, const float* __restrict__ B1,
                                                     unsigned short* __restrict__ Hb) {
  int e = blockIdx.z;
  int n0 = blockIdx.x * 64, m0 = blockIdx.y * 64;
  __shared__ short As[64 * 72];
  __shared__ short Ws[64 * 72];
  __shared__ int rowIdx[64];
  int t = threadIdx.x;
  if (t < 64) {
    int r = m0 + t;
    int ri = (r < PB) ? pairs[(size_t)e * PB + r] : -1;
    if ((unsigned)ri >= (unsigned)nTok) ri = -1;
    rowIdx[t] = ri;
  }
  __syncthreads();
  int sr = t >> 2, sc = (t & 3) * 16;
  const float* Wrow = W1 + (size_t)e * I * H + (size_t)(n0 + sr) * H;
  int ri = rowIdx[sr];
  const float* Xrow = (ri >= 0) ? X + (size_t)ri * H : nullptr;
  int w = t >> 6, lane = t & 63;
  int wm = (w >> 1) * 32, wn = (w & 1) * 32;
  int frow = lane & 15, quad = lane >> 4;
  f32x4 acc[2][2] = {};
  for (int k0 = 0; k0 < H; k0 += 64) {
    // stage A (gathered fp32 -> bf16)
    {
      f32x4 f0 = {}, f1 = {}, f2 = {}, f3 = {};
      if (Xrow) {
        const f32x4* sp = (const f32x4*)(Xrow + k0 + sc);
        f0 = sp[0]; f1 = sp[1]; f2 = sp[2]; f3 = sp[3];
      }
      i32x4 lo, hi;
      lo.x = pack2(f0.x, f0.y); lo.y = pack2(f0.z, f0.w);
      lo.z = pack2(f1.x, f1.y); lo.w = pack2(f1.z, f1.w);
      hi.x = pack2(f2.x, f2.y); hi.y = pack2(f2.z, f2.w);
      hi.z = pack2(f3.x, f3.y); hi.w = pack2(f3.z, f3.w);
      *(i32x4*)(&As[sr * 72 + sc]) = lo;
      *(i32x4*)(&As[sr * 72 + sc + 8]) = hi;
    }
    // stage W (fp32 -> bf16)
    {
      const f32x4* sp = (const f32x4*)(Wrow + k0 + sc);
      f32x4 f0 = sp[0], f1 = sp[1], f2 = sp[2], f3 = sp[3];
      i32x4 lo, hi;
      lo.x = pack2(f0.x, f0.y); lo.y = pack2(f0.z, f0.w);
      lo.z = pack2(f1.x, f1.y); lo.w = pack2(f1.z, f1.w);
      hi.x = pack2(f2.x, f2.y); hi.y = pack2(f2.z, f2.w);
      hi.z = pack2(f3.x, f3.y); hi.w = pack2(f3.z, f3.w);
      *(i32x4*)(&Ws[sr * 72 + sc]) = lo;
      *(i32x4*)(&Ws[sr * 72 + sc + 8]) = hi;
    }
    __syncthreads();
#pragma unroll
    for (int ks = 0; ks < 64; ks += 32) {
      bf16x8 a0 = *(bf16x8*)(&As[(wm + frow) * 72 + ks + quad * 8]);
      bf16x8 a1 = *(bf16x8*)(&As[(wm + 16 + frow) * 72 + ks + quad * 8]);
      bf16x8 b0 = *(bf16x8*)(&Ws[(wn + frow) * 72 + ks + quad * 8]);
      bf16x8 b1 = *(bf16x8*)(&Ws[(wn + 16 + frow) * 72 + ks + quad * 8]);
      acc[0][0] = MFMA_BF16(a0, b0, acc[0][0], 0, 0, 0);
      acc[0][1] = MFMA_BF16(a0, b1, acc[0][1], 0, 0, 0);
      acc[1][0] = MFMA_BF16(a1, b0, acc[1][0], 0, 0, 0);
      acc[1][1] = MFMA_BF16(a1, b1, acc[1][1], 0, 0, 0);
    }
    __syncthreads();
  }
  const float* b1p = B1 + (size_t)e * I;
#pragma unroll
  for (int i = 0; i < 2; ++i) {
#pragma unroll
    for (int j = 0; j < 2; ++j) {
      int n = n0 + wn + j * 16 + frow;
      float bias = b1p[n];
#pragma unroll
      for (int reg = 0; reg < 4; ++reg) {
        int r = m0 + wm + i * 16 + quad * 4 + reg;
        if (r < PB) {
          float v = gelu_f(acc[i][j][reg] + bias);
          Hb[((size_t)e * PB + r) * I + n] = (unsigned short)f2bf_u(v);
        }
      }
    }
  }
}

// down: ACC[tok][H] += gather-scatter( Hb_e @ W2_e^T + b2_e )
__global__ __launch_bounds__(256) void k_moe_down_mfma(const unsigned short* __restrict__ Hb, int nTok,
                                                       const int* __restrict__ pairs, int PB,
                                                       const float* __restrict__ W2, const float* __restrict__ B2,
                                                       float* __restrict__ ACC) {
  int e = blockIdx.z;
  int n0 = blockIdx.x * 64, m0 = blockIdx.y * 64;
  __shared__ short As[64 * 72];
  __shared__ short Ws[64 * 72];
  __shared__ int tokLds[64];
  int t = threadIdx.x;
  if (t < 64) {
    int r = m0 + t;
    int tk = (r < PB) ? pairs[(size_t)e * PB + r] : 0;
    if ((unsigned)tk >= (unsigned)nTok) tk = 0;
    tokLds[t] = tk;
  }
  __syncthreads();
  int sr = t >> 2, sc = (t & 3) * 16;
  bool arow_ok = (m0 + sr) < PB;
  const unsigned short* Arow = Hb + ((size_t)e * PB + (m0 + sr)) * I;
  const float* Wrow = W2 + (size_t)e * H * I + (size_t)(n0 + sr) * I;
  int w = t >> 6, lane = t & 63;
  int wm = (w >> 1) * 32, wn = (w & 1) * 32;
  int frow = lane & 15, quad = lane >> 4;
  f32x4 acc[2][2] = {};
  for (int k0 = 0; k0 < I; k0 += 64) {
    // stage A (bf16 direct copy)
    {
      i32x4 lo = {}, hi = {};
      if (arow_ok) {
        const i32x4* sp = (const i32x4*)(Arow + k0 + sc);
        lo = sp[0]; hi = sp[1];
      }
      *(i32x4*)(&As[sr * 72 + sc]) = lo;
      *(i32x4*)(&As[sr * 72 + sc + 8]) = hi;
    }
    // stage W (fp32 -> bf16)
    {
      const f32x4* sp = (const f32x4*)(Wrow + k0 + sc);
      f32x4 f0 = sp[0], f1 = sp[1], f2 = sp[2], f3 = sp[3];
      i32x4 lo, hi;
      lo.x = pack2(f0.x, f0.y); lo.y = pack2(f0.z, f0.w);
      lo.z = pack2(f1.x, f1.y); lo.w = pack2(f1.z, f1.w);
      hi.x = pack2(f2.x, f2.y); hi.y = pack2(f2.z, f2.w);
      hi.z = pack2(f3.x, f3.y); hi.w = pack2(f3.z, f3.w);
      *(i32x4*)(&Ws[sr * 72 + sc]) = lo;
      *(i32x4*)(&Ws[sr * 72 + sc + 8]) = hi;
    }
    __syncthreads();
#pragma unroll
    for (int ks = 0; ks < 64; ks += 32) {
      bf16x8 a0 = *(bf16x8*)(&As[(wm + frow) * 72 + ks + quad * 8]);
      bf16x8 a1 = *(bf16x8*)(&As[(wm + 16 + frow) * 72 + ks + quad * 8]);
      bf16x8 b0 = *(bf16x8*)(&Ws[(wn + frow) * 72 + ks + quad * 8]);
      bf16x8 b1 = *(bf16x8*)(&Ws[(wn + 16 + frow) * 72 + ks + quad * 8]);
      acc[0][0] = MFMA_BF16(a0, b0, acc[0][0], 0, 0, 0);
      acc[0][1] = MFMA_BF16(a0, b1, acc[0][1], 0, 0, 0);
      acc[1][0] = MFMA_BF16(a1, b0, acc[1][0], 0, 0, 0);
      acc[1][1] = MFMA_BF16(a1, b1, acc[1][1], 0, 0, 0);
    }
    __syncthreads();
  }
  const float* b2p = B2 + (size_t)e * H;
#pragma unroll
  for (int i = 0; i < 2; ++i) {
#pragma unroll
    for (int j = 0; j < 2; ++j) {
      int n = n0 + wn + j * 16 + frow;
      float bias = b2p[n];
#pragma unroll
      for (int reg = 0; reg < 4; ++reg) {
        int r = m0 + wm + i * 16 + quad * 4 + reg;
        if (r < PB) {
          int tok = tokLds[wm + i * 16 + quad * 4 + reg];
          atomicAdd(&ACC[(size_t)tok * H + n], acc[i][j][reg] + bias);
        }
      }
    }
  }
}

// ---------------- final ----------------
__global__ __launch_bounds__(256) void k_final(const float* __restrict__ base, const float* __restrict__ acc,
                                               const int* __restrict__ cnt, float* __restrict__ out, int n) {
  int i = blockIdx.x * 256 + threadIdx.x;
  if (i >= n) return;
  int row = i >> 10;
  int c = cnt[row]; if (c < 1) c = 1;
  out[i] = base[i] + acc[i] / (float)c;
}

extern "C" void kernel_launch(void* const* d_in, const int* in_sizes, int n_in,
                              void* d_out, int out_size, void* d_ws, size_t ws_size,
                              hipStream_t stream) {
  float* out = (float*)d_out;
  dim3 blk(256);
  const int OUT_N = (int)(FQ + FIMG);
  int outN = out_size;

  static const int EXP[25] = {
    B * T * H, B * V * H, B * L * H,
    3 * H * H, 3 * H, H * H, H,
    3 * H * H, 3 * H, H * H, H,
    E * 2 * H, E, E * 2 * H, E,
    E * I * H, E * I, E * H * I, E * H,
    H, H, H, H, H, H
  };
  if (n_in != 25) { k_diag<<<dim3((outN + 255) / 256), blk, 0, stream>>>(out, outN, 40000.f); return; }
  for (int i = 0; i < 25; ++i)
    if (in_sizes[i] != EXP[i]) {
      k_diag<<<dim3((outN + 255) / 256), blk, 0, stream>>>(out, outN, 20000.f + 1000.f * i);
      return;
    }
  if (out_size != OUT_N) { k_diag<<<dim3((outN + 255) / 256), blk, 0, stream>>>(out, outN, 30000.f); return; }
  if (ws_size < WS_FLOATS * sizeof(float)) {
    k_diag<<<dim3((outN + 255) / 256), blk, 0, stream>>>(out, outN, 12345.f);
    return;
  }

  float* wsf = (float*)d_ws;
  float* Q = wsf + oQ;  float* XN = wsf + oXN;  float* AO = wsf + oAO;  float* IMG32 = wsf + oIMG;
  float* CTXI = wsf + oCTXI;  float* CTXT = wsf + oCTXT;
  float* PRT = wsf + oPRT;    float* PRI = wsf + oPRI;
  float* SW = wsf + oSW;
  int* FLAG = (int*)(wsf + oINT);
  int* PAIRS_T = FLAG + 1;
  int* PAIRS_I = PAIRS_T + E * PBT;
  int* CNT_T = PAIRS_I + E * PBI;
  int* CNT_I = CNT_T + B * T;
  float* QKV = wsf + oBIG;                       // attention phase
  unsigned short* HBu = (unsigned short*)(wsf + oBIG);  // MoE phase (QKV dead)

  k_detect<<<dim3(1), blk, 0, stream>>>(d_in[0], FLAG);

  // fused small-weight conversions (16 segments, prefix-contiguous in SW)
  {
    CvtTab tab;
    const int srcIdx[16] = {4, 6, 8, 10, 11, 12, 13, 14, 16, 18, 19, 20, 21, 22, 23, 24};
    const int starts[17] = {(int)sSA_B_IN, (int)sSA_B_OUT, (int)sCA_B_IN, (int)sCA_B_OUT,
                            (int)sGIW, (int)sGIB, (int)sGTW, (int)sGTB,
                            (int)sEB1, (int)sEB2,
                            (int)sLNQG, (int)sLNQB, (int)sLNCG, (int)sLNCB, (int)sLNFG, (int)sLNFB,
                            (int)SWN};
    for (int c = 0; c < 16; ++c) tab.src[c] = d_in[srcIdx[c]];
    for (int c = 0; c < 17; ++c) tab.start[c] = starts[c];
    k_cvt_multi<<<dim3(((int)SWN + 255) / 256), blk, 0, stream>>>(tab, SW, FLAG);
  }

  k_cvt2<<<dim3((int)(FQ / 256)), blk, 0, stream>>>(d_in[0], Q, (int)FQ, FLAG);
  k_cvt2<<<dim3((int)(FIMG / 256)), blk, 0, stream>>>(d_in[1], IMG32, (int)FIMG, FLAG);

  // ---- 1) self-attention ----
  k_ln<<<dim3(B * T), blk, 0, stream>>>(Q, SW + sLNQG, SW + sLNQB, XN);
  k_gemm<128, 128, false><<<dim3(3 * H / 128, B * T / 128), blk, 0, stream>>>(
      XN, H, d_in[3], 0, H, SW + sSA_B_IN, QKV, 3 * H, B * T, 3 * H, H, FLAG);
  k_attn_tile<<<dim3(T / 64, NH, B), blk, 0, stream>>>(QKV, 3 * H, QKV + H, 3 * H, QKV + 2 * H, 3 * H, AO, T, T);
  k_gemm<128, 64, true><<<dim3(H / 64, B * T / 128), blk, 0, stream>>>(
      AO, H, d_in[5], 0, H, SW + sSA_B_OUT, Q, H, B * T, H, H, FLAG);

  // ---- 2) cross-attention ----
  k_ln<<<dim3(B * T), blk, 0, stream>>>(Q, SW + sLNCG, SW + sLNCB, XN);
  k_gemm<128, 64, false><<<dim3(H / 64, B * T / 128), blk, 0, stream>>>(
      XN, H, d_in[7], 0, H, SW + sCA_B_IN, QKV, H, B * T, H, H, FLAG);
  k_gemm<128, 128, false><<<dim3(2 * H / 128, B * V / 128), blk, 0, stream>>>(
      IMG32, H, d_in[7], (size_t)H * H, H, SW + sCA_B_IN + H, QKV + FQ, 2 * H, B * V, 2 * H, H, FLAG);
  k_attn_tile<<<dim3(T / 64, NH, B), blk, 0, stream>>>(QKV, H, QKV + FQ, 2 * H, QKV + FQ + H, 2 * H, AO, T, V);
  k_gemm<128, 64, true><<<dim3(H / 64, B * T / 128), blk, 0, stream>>>(
      AO, H, d_in[9], 0, H, SW + sCA_B_OUT, Q, H, B * T, H, H, FLAG);

  // ---- 3) gating ----
  k_mean_f32<<<dim3((B * H) / 256), blk, 0, stream>>>(IMG32, CTXI, V);
  k_mean_in<<<dim3((B * H) / 256), blk, 0, stream>>>(d_in[2], CTXT, L, FLAG);
  k_gate<<<dim3(B * T), blk, 0, stream>>>(Q, CTXI, SW + sGTW, SW + sGTB, PRT, T);
  k_gate<<<dim3(B * V), blk, 0, stream>>>(IMG32, CTXT, SW + sGIW, SW + sGIB, PRI, V);
  k_zeroi<<<dim3((B * T + B * V + 255) / 256), blk, 0, stream>>>(CNT_T, B * T + B * V);

  // ---- 4) top-k for BOTH streams (one dispatch, wave-parallel, barrier-free) ----
  k_topk2<<<dim3(16), blk, 0, stream>>>(PRT, PRI, PAIRS_T, PAIRS_I, CNT_T, CNT_I);

  // ---- 5) text MoE (MFMA) ----
  k_ln<<<dim3(B * T), blk, 0, stream>>>(Q, SW + sLNFG, SW + sLNFB, XN);
  k_zerof<<<dim3((int)(FQ / 256)), blk, 0, stream>>>(AO, (int)FQ);
  k_moe_up_mfma<<<dim3(I / 64, PBT / 64, E), blk, 0, stream>>>(
      XN, B * T, PAIRS_T, PBT, (const float*)d_in[15], (const float*)d_in[16], HBu);
  k_moe_down_mfma<<<dim3(H / 64, PBT / 64, E), blk, 0, stream>>>(
      HBu, B * T, PAIRS_T, PBT, (const float*)d_in[17], (const float*)d_in[18], AO);
  k_final<<<dim3((int)(FQ / 256)), blk, 0, stream>>>(Q, AO, CNT_T, out, (int)FQ);

  // ---- 6) image MoE (MFMA) ----
  k_zerof<<<dim3((int)(FIMG / 256)), blk, 0, stream>>>(AO, (int)FIMG);
  k_moe_up_mfma<<<dim3(I / 64, (PBI + 63) / 64, E), blk, 0, stream>>>(
      IMG32, B * V, PAIRS_I, PBI, (const float*)d_in[15], (const float*)d_in[16], HBu);
  k_moe_down_mfma<<<dim3(H / 64, (PBI + 63) / 64, E), blk, 0, stream>>>(
      HBu, B * V, PAIRS_I, PBI, (const float*)d_in[17], (const float*)d_in[18], AO);
  k_final<<<dim3((int)(FIMG / 256)), blk, 0, stream>>>(IMG32, AO, CNT_I, out + FQ, (int)FIMG);
}

// Round 4
// 1594.681 us; speedup vs baseline: 2.3506x; 1.2702x over previous
//
#include <hip/hip_runtime.h>
#include <hip/hip_bf16.h>

using bf16 = __hip_bfloat16;

namespace {
constexpr int B = 4, T = 512, V = 576, L = 256, H = 1024, NH = 16, HD = 64, I = 4096, E = 8;
constexpr int KT = 80;          // int(1.25*512 + 7) // 8 = 80
constexpr int KI = 90;          // int(1.25*576 + 7) // 8 = 90
constexpr int PBT = B * KT;     // 320
constexpr int PBI = B * KI;     // 360

constexpr size_t FQ   = (size_t)B * T * H;   // 2,097,152
constexpr size_t FIMG = (size_t)B * V * H;   // 2,359,296
constexpr size_t FQKV = FQ + (size_t)B * V * 2 * H;  // 6,815,744
constexpr size_t FHB  = (size_t)E * PBI * I;         // 11,796,480 (bf16 elems in MoE phase)

// small-weight (fp32-converted) region offsets (prefix-contiguous)
constexpr size_t sSA_B_IN = 0, sSA_B_OUT = 3072, sCA_B_IN = 4096, sCA_B_OUT = 7168;
constexpr size_t sGIW = 8192, sGIB = 24576, sGTW = 24584, sGTB = 40968;
constexpr size_t sEB1 = 40976, sEB2 = 73744;
constexpr size_t sLNQG = 81936, sLNQB = 82960, sLNCG = 83984, sLNCB = 85008, sLNFG = 86032, sLNFB = 87056;
constexpr size_t SWN = 88080;

// ws layout (float offsets)
constexpr size_t oQ = 0, oXN = oQ + FQ, oAO = oXN + FQ, oIMG = oAO + FIMG;
constexpr size_t oCTXI = oIMG + FIMG, oCTXT = oCTXI + (size_t)B * H;
constexpr size_t oPRT = oCTXT + (size_t)B * H, oPRI = oPRT + (size_t)B * T * E;
constexpr size_t oSW = oPRI + (size_t)B * V * E;
constexpr size_t oINT = oSW + SWN;                      // int region (flag + pairs + counts)
constexpr size_t oBIG = oINT + 16384;                   // QKV(f32) / HB(bf16) union
constexpr size_t WS_FLOATS = oBIG + (FQKV > FHB ? FQKV : FHB);
}

typedef __attribute__((ext_vector_type(8))) short bf16x8;
typedef __attribute__((ext_vector_type(4))) float f32x4;
typedef __attribute__((ext_vector_type(4))) int i32x4;

__device__ __forceinline__ float b2f(bf16 x) { return __bfloat162float(x); }

__device__ __forceinline__ float ldany(const void* p, int f32, size_t idx) {
  return f32 ? ((const float*)p)[idx] : b2f(((const bf16*)p)[idx]);
}

__device__ __forceinline__ unsigned int f2bf_u(float v) {   // RNE fp32->bf16 bits
  unsigned int u = __float_as_uint(v);
  u += 0x7FFFu + ((u >> 16) & 1u);
  return u >> 16;
}
__device__ __forceinline__ int pack2(float a, float b) {
  return (int)(f2bf_u(a) | (f2bf_u(b) << 16));
}

__device__ __forceinline__ float gelu_f(float x) {
  float x3 = x * x * x;
  return 0.5f * x * (1.f + tanhf(0.7978845608028654f * (x + 0.044715f * x3)));
}

// split one fp32 vec4 chunk x4 (16 floats) into bf16 hi/lo words
__device__ __forceinline__ void split16(const f32x4* __restrict__ sp,
                                        short* __restrict__ hiDst, short* __restrict__ loDst) {
  int hw[8], lw[8];
#pragma unroll
  for (int u = 0; u < 4; ++u) {
    f32x4 v = sp[u];
    unsigned h0 = f2bf_u(v.x), h1 = f2bf_u(v.y), h2 = f2bf_u(v.z), h3 = f2bf_u(v.w);
    float r0 = v.x - __uint_as_float(h0 << 16);
    float r1 = v.y - __uint_as_float(h1 << 16);
    float r2 = v.z - __uint_as_float(h2 << 16);
    float r3 = v.w - __uint_as_float(h3 << 16);
    hw[u * 2 + 0] = (int)(h0 | (h1 << 16));
    hw[u * 2 + 1] = (int)(h2 | (h3 << 16));
    lw[u * 2 + 0] = pack2(r0, r1);
    lw[u * 2 + 1] = pack2(r2, r3);
  }
  ((i32x4*)hiDst)[0] = *(i32x4*)&hw[0];
  ((i32x4*)hiDst)[1] = *(i32x4*)&hw[4];
  ((i32x4*)loDst)[0] = *(i32x4*)&lw[0];
  ((i32x4*)loDst)[1] = *(i32x4*)&lw[4];
}

// ---------------- dtype probe ----------------
__global__ __launch_bounds__(256) void k_detect(const void* __restrict__ q, int* __restrict__ flag) {
  __shared__ int cnt;
  if (threadIdx.x == 0) cnt = 0;
  __syncthreads();
  int local = 0;
  for (int i = threadIdx.x; i < 65536; i += 256) {
    float v = b2f(((const bf16*)q)[i]);
    if (!(fabsf(v) < 1e4f)) local++;
  }
  atomicAdd(&cnt, local);
  __syncthreads();
  if (threadIdx.x == 0) *flag = (cnt > 64) ? 1 : 0;
}

__global__ __launch_bounds__(256) void k_cvt2(const void* __restrict__ in, float* __restrict__ out,
                                              int n, const int* __restrict__ flag) {
  int f32 = *flag;
  int i = blockIdx.x * 256 + threadIdx.x;
  if (i < n) out[i] = ldany(in, f32, (size_t)i);
}

// fused 16-segment small-weight conversion (segments are prefix-contiguous in dst)
struct CvtTab { const void* src[16]; int start[17]; };
__global__ __launch_bounds__(256) void k_cvt_multi(CvtTab tab, float* __restrict__ out,
                                                   const int* __restrict__ flag) {
  int f32 = *flag;
  int i = blockIdx.x * 256 + threadIdx.x;
  if (i >= (int)SWN) return;
  int lo = 0, hi = 15;
  while (lo < hi) { int mid = (lo + hi + 1) >> 1; if (i >= tab.start[mid]) lo = mid; else hi = mid - 1; }
  out[i] = ldany(tab.src[lo], f32, (size_t)(i - tab.start[lo]));
}

__global__ __launch_bounds__(256) void k_zerof(float* __restrict__ p, int n) {
  int i = blockIdx.x * 256 + threadIdx.x;
  if (i < n) p[i] = 0.f;
}
__global__ __launch_bounds__(256) void k_zeroi(int* __restrict__ p, int n) {
  int i = blockIdx.x * 256 + threadIdx.x;
  if (i < n) p[i] = 0;
}
__global__ __launch_bounds__(256) void k_diag(float* __restrict__ out, int n, float code) {
  int i = blockIdx.x * 256 + threadIdx.x;
  if (i < n) out[i] = (i == 0 ? code : 0.f);
}

// ---------------- LayerNorm ----------------
__global__ __launch_bounds__(256) void k_ln(const float* __restrict__ X,
                                            const float* __restrict__ g, const float* __restrict__ bta,
                                            float* __restrict__ Y) {
  int row = blockIdx.x;
  const float* x = X + (size_t)row * H;
  float s = 0.f, ss = 0.f;
  for (int j = threadIdx.x; j < H; j += 256) { float v = x[j]; s += v; ss += v * v; }
#pragma unroll
  for (int off = 32; off; off >>= 1) { s += __shfl_xor(s, off); ss += __shfl_xor(ss, off); }
  __shared__ float ls[4], lss[4];
  __shared__ float mean_s, inv_s;
  int w = threadIdx.x >> 6, lane = threadIdx.x & 63;
  if (lane == 0) { ls[w] = s; lss[w] = ss; }
  __syncthreads();
  if (threadIdx.x == 0) {
    float S1 = ls[0] + ls[1] + ls[2] + ls[3];
    float S2 = lss[0] + lss[1] + lss[2] + lss[3];
    float m = S1 / (float)H;
    float var = S2 / (float)H - m * m;
    mean_s = m;
    inv_s = 1.f / sqrtf(var + 1e-5f);
  }
  __syncthreads();
  float m = mean_s, inv = inv_s;
  float* y = Y + (size_t)row * H;
  for (int j = threadIdx.x; j < H; j += 256)
    y[j] = (x[j] - m) * inv * g[j] + bta[j];
}

#define MFMA_BF16 __builtin_amdgcn_mfma_f32_16x16x32_bf16

// ---------------- split-bf16 MFMA GEMM (attention path, ~fp32 precision) ----------------
// C[m][n] = sum_k A[m][k] * W[n][k] + bias[n]  (optionally += C)
// Each fp32 operand split as hi(bf16) + lo(bf16); product = hh + hl + lh via 3 MFMA,
// fp32 accumulation. Dropped lo*lo term ~2^-18 relative. Structure cloned from the
// proven MoE MFMA kernel: 64x64 tile, BK=64, 4 waves of 32x32 (2x2 16x16x32 frags).
// LDS row = [hi 64 | lo 64 | pad 8] bf16 -> 272 B stride (16B-aligned, 2-way banks).
// M, N must be multiples of 64; K multiple of 64. No guards.
template <bool ADD>
__global__ __launch_bounds__(256) void k_gemm_sp(const float* __restrict__ A, int lda,
                                                 const void* __restrict__ W, size_t wOff, int ldw,
                                                 const float* __restrict__ bias,
                                                 float* __restrict__ C, int ldc,
                                                 int M, int N, int K, const int* __restrict__ flag) {
  __shared__ __align__(16) short As[64 * 136];
  __shared__ __align__(16) short Ws[64 * 136];
  int f32 = *flag;
  int n0 = blockIdx.x * 64, m0 = blockIdx.y * 64;
  int t = threadIdx.x;
  int sr = t >> 2, sc = (t & 3) * 16;
  const float* Arow = A + (size_t)(m0 + sr) * lda + sc;
  const float* WrowF = (const float*)W + wOff + (size_t)(n0 + sr) * ldw + sc;
  const bf16*  WrowH = (const bf16*)W + wOff + (size_t)(n0 + sr) * ldw + sc;
  int w = t >> 6, lane = t & 63;
  int wm = (w >> 1) * 32, wn = (w & 1) * 32;
  int frow = lane & 15, quad = lane >> 4;
  f32x4 acc[2][2] = {};
  for (int k0 = 0; k0 < K; k0 += 64) {
    // stage A (fp32 -> hi/lo bf16)
    split16((const f32x4*)(Arow + k0), &As[sr * 136 + sc], &As[sr * 136 + 64 + sc]);
    // stage W (fp32 fast path -> hi/lo; bf16 fallback -> hi only, lo = 0)
    if (f32) {
      split16((const f32x4*)(WrowF + k0), &Ws[sr * 136 + sc], &Ws[sr * 136 + 64 + sc]);
    } else {
      const i32x4* sp = (const i32x4*)(WrowH + k0);
      ((i32x4*)&Ws[sr * 136 + sc])[0] = sp[0];
      ((i32x4*)&Ws[sr * 136 + sc])[1] = sp[1];
      i32x4 z = {};
      ((i32x4*)&Ws[sr * 136 + 64 + sc])[0] = z;
      ((i32x4*)&Ws[sr * 136 + 64 + sc])[1] = z;
    }
    __syncthreads();
#pragma unroll
    for (int ks = 0; ks < 64; ks += 32) {
      bf16x8 a0h = *(bf16x8*)(&As[(wm + frow) * 136 + ks + quad * 8]);
      bf16x8 a1h = *(bf16x8*)(&As[(wm + 16 + frow) * 136 + ks + quad * 8]);
      bf16x8 a0l = *(bf16x8*)(&As[(wm + frow) * 136 + 64 + ks + quad * 8]);
      bf16x8 a1l = *(bf16x8*)(&As[(wm + 16 + frow) * 136 + 64 + ks + quad * 8]);
      bf16x8 b0h = *(bf16x8*)(&Ws[(wn + frow) * 136 + ks + quad * 8]);
      bf16x8 b1h = *(bf16x8*)(&Ws[(wn + 16 + frow) * 136 + ks + quad * 8]);
      bf16x8 b0l = *(bf16x8*)(&Ws[(wn + frow) * 136 + 64 + ks + quad * 8]);
      bf16x8 b1l = *(bf16x8*)(&Ws[(wn + 16 + frow) * 136 + 64 + ks + quad * 8]);
      acc[0][0] = MFMA_BF16(a0h, b0h, acc[0][0], 0, 0, 0);
      acc[0][1] = MFMA_BF16(a0h, b1h, acc[0][1], 0, 0, 0);
      acc[1][0] = MFMA_BF16(a1h, b0h, acc[1][0], 0, 0, 0);
      acc[1][1] = MFMA_BF16(a1h, b1h, acc[1][1], 0, 0, 0);
      acc[0][0] = MFMA_BF16(a0h, b0l, acc[0][0], 0, 0, 0);
      acc[0][1] = MFMA_BF16(a0h, b1l, acc[0][1], 0, 0, 0);
      acc[1][0] = MFMA_BF16(a1h, b0l, acc[1][0], 0, 0, 0);
      acc[1][1] = MFMA_BF16(a1h, b1l, acc[1][1], 0, 0, 0);
      acc[0][0] = MFMA_BF16(a0l, b0h, acc[0][0], 0, 0, 0);
      acc[0][1] = MFMA_BF16(a0l, b1h, acc[0][1], 0, 0, 0);
      acc[1][0] = MFMA_BF16(a1l, b0h, acc[1][0], 0, 0, 0);
      acc[1][1] = MFMA_BF16(a1l, b1h, acc[1][1], 0, 0, 0);
    }
    __syncthreads();
  }
#pragma unroll
  for (int i = 0; i < 2; ++i)
#pragma unroll
    for (int j = 0; j < 2; ++j) {
      int n = n0 + wn + j * 16 + frow;
      float bv = bias[n];
#pragma unroll
      for (int reg = 0; reg < 4; ++reg) {
        int gm = m0 + wm + i * 16 + quad * 4 + reg;
        float v = acc[i][j][reg] + bv;
        size_t o = (size_t)gm * ldc + n;
        if (ADD) v += C[o];
        C[o] = v;
      }
    }
}

// ---------------- flash-tiled attention (fp32, 64-query tile per block) ----------------
__global__ __launch_bounds__(256) void k_attn_tile(const float* __restrict__ Qb, int qStride,
                                                   const float* __restrict__ Kb, int kStride,
                                                   const float* __restrict__ Vb, int vStride,
                                                   float* __restrict__ Ob, int Tq, int Tk) {
  int h = blockIdx.y, b = blockIdx.z;
  int q0 = blockIdx.x * 64;
  __shared__ float Qt[64][68];   // [d][q]
  __shared__ float KV[64][68];   // S phase: [d][k]; PV phase: [k][d]
  __shared__ float Ps[64][68];   // [q][k]
  int t = threadIdx.x;
  int tm = t >> 4, tn = t & 15;
  int sr = t >> 2, c0 = (t & 3) * 16;   // staging: row sr (0..63), 16-float chunk c0

  // stage Q transposed (once)
  {
    const float* src = Qb + ((size_t)(b * Tq + q0 + sr)) * qStride + h * HD + c0;
#pragma unroll
    for (int u = 0; u < 4; ++u) {
      f32x4 v = *(const f32x4*)(src + u * 4);
      Qt[c0 + u * 4 + 0][sr] = v.x;
      Qt[c0 + u * 4 + 1][sr] = v.y;
      Qt[c0 + u * 4 + 2][sr] = v.z;
      Qt[c0 + u * 4 + 3][sr] = v.w;
    }
  }

  float m[4], l[4];
  f32x4 oacc[4] = {};
#pragma unroll
  for (int i = 0; i < 4; ++i) { m[i] = -1e30f; l[i] = 0.f; }

  for (int k0 = 0; k0 < Tk; k0 += 64) {
    // stage K tile transposed into KV[d][k]
    {
      const float* src = Kb + ((size_t)(b * Tk + k0 + sr)) * kStride + h * HD + c0;
#pragma unroll
      for (int u = 0; u < 4; ++u) {
        f32x4 v = *(const f32x4*)(src + u * 4);
        KV[c0 + u * 4 + 0][sr] = v.x;
        KV[c0 + u * 4 + 1][sr] = v.y;
        KV[c0 + u * 4 + 2][sr] = v.z;
        KV[c0 + u * 4 + 3][sr] = v.w;
      }
    }
    __syncthreads();
    // S = Q.K^T, thread tile 4x4
    float sacc[4][4] = {};
#pragma unroll 8
    for (int d = 0; d < 64; ++d) {
      f32x4 a = *(const f32x4*)(&Qt[d][tm * 4]);
      f32x4 bb = *(const f32x4*)(&KV[d][tn * 4]);
#pragma unroll
      for (int i = 0; i < 4; ++i)
#pragma unroll
        for (int j = 0; j < 4; ++j) sacc[i][j] = fmaf(a[i], bb[j], sacc[i][j]);
    }
    __syncthreads();   // everyone done reading K from KV
    // stage V tile natural into KV[k][d]
    {
      const float* src = Vb + ((size_t)(b * Tk + k0 + sr)) * vStride + h * HD + c0;
#pragma unroll
      for (int u = 0; u < 4; ++u)
        *(f32x4*)(&KV[sr][c0 + u * 4]) = *(const f32x4*)(src + u * 4);
    }
    // online softmax in registers
#pragma unroll
    for (int i = 0; i < 4; ++i) {
      float rm = -1e30f;
#pragma unroll
      for (int j = 0; j < 4; ++j) { sacc[i][j] *= 0.125f; rm = fmaxf(rm, sacc[i][j]); }
#pragma unroll
      for (int off = 1; off < 16; off <<= 1) rm = fmaxf(rm, __shfl_xor(rm, off));
      float mnew = fmaxf(m[i], rm);
      float rs = 0.f;
#pragma unroll
      for (int j = 0; j < 4; ++j) { float p = __expf(sacc[i][j] - mnew); sacc[i][j] = p; rs += p; }
#pragma unroll
      for (int off = 1; off < 16; off <<= 1) rs += __shfl_xor(rs, off);
      float scl = __expf(m[i] - mnew);
      l[i] = l[i] * scl + rs;
      m[i] = mnew;
#pragma unroll
      for (int j = 0; j < 4; ++j) oacc[i][j] *= scl;
      f32x4 pv;
      pv.x = sacc[i][0]; pv.y = sacc[i][1]; pv.z = sacc[i][2]; pv.w = sacc[i][3];
      *(f32x4*)(&Ps[tm * 4 + i][tn * 4]) = pv;
    }
    __syncthreads();   // Ps written, V staged
    // O += P @ V
#pragma unroll 4
    for (int kk = 0; kk < 64; kk += 4) {
      f32x4 a[4];
#pragma unroll
      for (int i = 0; i < 4; ++i) a[i] = *(const f32x4*)(&Ps[tm * 4 + i][kk]);
#pragma unroll
      for (int u = 0; u < 4; ++u) {
        f32x4 vv = *(const f32x4*)(&KV[kk + u][tn * 4]);
#pragma unroll
        for (int i = 0; i < 4; ++i)
#pragma unroll
          for (int j = 0; j < 4; ++j) oacc[i][j] = fmaf(a[i][u], vv[j], oacc[i][j]);
      }
    }
    __syncthreads();   // done reading KV(V)/Ps before next tile restages
  }
#pragma unroll
  for (int i = 0; i < 4; ++i) {
    float inv = 1.f / l[i];
    f32x4 r;
#pragma unroll
    for (int j = 0; j < 4; ++j) r[j] = oacc[i][j] * inv;
    *(f32x4*)(Ob + ((size_t)(b * Tq + q0 + tm * 4 + i)) * H + h * HD + tn * 4) = r;
  }
}

// ---------------- means ----------------
__global__ __launch_bounds__(256) void k_mean_f32(const float* __restrict__ X, float* __restrict__ out, int S) {
  int i = blockIdx.x * 256 + threadIdx.x;
  int b = i >> 10, d = i & (H - 1);
  const float* p = X + (size_t)b * S * H + d;
  float s = 0.f;
  for (int t = 0; t < S; ++t) s += p[(size_t)t * H];
  out[i] = s / (float)S;
}
__global__ __launch_bounds__(256) void k_mean_in(const void* __restrict__ X, float* __restrict__ out,
                                                 int S, const int* __restrict__ flag) {
  int f32 = *flag;
  int i = blockIdx.x * 256 + threadIdx.x;
  int b = i >> 10, d = i & (H - 1);
  size_t base = (size_t)b * S * H + d;
  float s = 0.f;
  for (int t = 0; t < S; ++t) s += ldany(X, f32, base + (size_t)t * H);
  out[i] = s / (float)S;
}

// ---------------- gate ----------------
__global__ __launch_bounds__(256) void k_gate(const float* __restrict__ X, const float* __restrict__ ctx,
                                              const float* __restrict__ Wg, const float* __restrict__ bg,
                                              float* __restrict__ probs, int S) {
  int row = blockIdx.x;
  int b = row / S;
  const float* xr = X + (size_t)row * H;
  const float* cx = ctx + (size_t)b * H;
  float p[E] = {};
  for (int j = threadIdx.x; j < 2 * H; j += 256) {
    float xv = (j < H) ? xr[j] : cx[j - H];
#pragma unroll
    for (int e = 0; e < E; ++e) p[e] += xv * Wg[(size_t)e * 2 * H + j];
  }
#pragma unroll
  for (int e = 0; e < E; ++e)
#pragma unroll
    for (int off = 32; off; off >>= 1) p[e] += __shfl_xor(p[e], off);
  __shared__ float gl[4][E];
  int w = threadIdx.x >> 6, lane = threadIdx.x & 63;
  if (lane == 0)
#pragma unroll
    for (int e = 0; e < E; ++e) gl[w][e] = p[e];
  __syncthreads();
  if (threadIdx.x == 0) {
    float lg[E], mx = -1e30f;
    for (int e = 0; e < E; ++e) {
      lg[e] = gl[0][e] + gl[1][e] + gl[2][e] + gl[3][e] + bg[e];
      mx = fmaxf(mx, lg[e]);
    }
    float ssum = 0.f;
    for (int e = 0; e < E; ++e) { lg[e] = __expf(lg[e] - mx); ssum += lg[e]; }
    float inv = 1.f / ssum;
    for (int e = 0; e < E; ++e) probs[(size_t)row * E + e] = lg[e] * inv;
  }
}

// ---------------- fused wave-parallel top-k (both streams, barrier-free) ----------------
__global__ __launch_bounds__(256) void k_topk2(const float* __restrict__ probsT, const float* __restrict__ probsI,
                                               int* __restrict__ pairsT, int* __restrict__ pairsI,
                                               int* __restrict__ cntT, int* __restrict__ cntI) {
  __shared__ float vals[4][640];
  int wv = threadIdx.x >> 6, lane = threadIdx.x & 63;
  int p = blockIdx.x * 4 + wv;             // 0..63
  int st = p >> 5, idx = p & 31;
  int e = idx >> 2, b = idx & 3;
  const float* probs = st ? probsI : probsT;
  int S  = st ? V : T;
  int k  = st ? KI : KT;
  int* pairs = st ? pairsI : pairsT;
  int* cnt   = st ? cntI : cntT;
  int PB = st ? PBI : PBT;
  float* v = vals[wv];
  for (int j = lane; j < S; j += 64) {
    float x = probs[((size_t)b * S + j) * E + e];
    v[j] = (x == x) ? x : -1e30f;
  }
  for (int it = 0; it < k; ++it) {
    float best = -2e30f; int besti = 0x7FFFFFFF;
    for (int j = lane; j < S; j += 64) {
      float x = v[j];
      if (x > best || (x == best && j < besti)) { best = x; besti = j; }
    }
#pragma unroll
    for (int off = 1; off < 64; off <<= 1) {
      float ob = __shfl_xor(best, off);
      int   oi = __shfl_xor(besti, off);
      if (ob > best || (ob == best && oi < besti)) { best = ob; besti = oi; }
    }
    int sidx = besti;
    if ((unsigned)sidx >= (unsigned)S) sidx = 0;
    if (lane == 0) {
      pairs[e * PB + b * k + it] = b * S + sidx;
      atomicAdd(&cnt[b * S + sidx], 1);
    }
    v[sidx] = -1e30f;   // all lanes, same addr, same value
  }
}

// ================= MFMA MoE =================
// 64x64 tile, 4 waves each computing 32x32 via 2x2 mfma_f32_16x16x32_bf16, BK=64.
// LDS row stride 72 bf16 (144 B): conflict-free b128 frag reads + int4 staging writes.

// up: Hb[e*PB+r][I] (bf16) = gelu(gather(X)[r] @ W1_e^T + b1_e)
__global__ __launch_bounds__(256) void k_moe_up_mfma(const float* __restrict__ X, int nTok,
                                                     const int* __restrict__ pairs, int PB,
                                                     const float* __restrict__ W1, const float* __restrict__ B1,
                                                     unsigned short* __restrict__ Hb) {
  int e = blockIdx.z;
  int n0 = blockIdx.x * 64, m0 = blockIdx.y * 64;
  __shared__ __align__(16) short As[64 * 72];
  __shared__ __align__(16) short Ws[64 * 72];
  __shared__ int rowIdx[64];
  int t = threadIdx.x;
  if (t < 64) {
    int r = m0 + t;
    int ri = (r < PB) ? pairs[(size_t)e * PB + r] : -1;
    if ((unsigned)ri >= (unsigned)nTok) ri = -1;
    rowIdx[t] = ri;
  }
  __syncthreads();
  int sr = t >> 2, sc = (t & 3) * 16;
  const float* Wrow = W1 + (size_t)e * I * H + (size_t)(n0 + sr) * H;
  int ri = rowIdx[sr];
  const float* Xrow = (ri >= 0) ? X + (size_t)ri * H : nullptr;
  int w = t >> 6, lane = t & 63;
  int wm = (w >> 1) * 32, wn = (w & 1) * 32;
  int frow = lane & 15, quad = lane >> 4;
  f32x4 acc[2][2] = {};
  for (int k0 = 0; k0 < H; k0 += 64) {
    // stage A (gathered fp32 -> bf16)
    {
      f32x4 f0 = {}, f1 = {}, f2 = {}, f3 = {};
      if (Xrow) {
        const f32x4* sp = (const f32x4*)(Xrow + k0 + sc);
        f0 = sp[0]; f1 = sp[1]; f2 = sp[2]; f3 = sp[3];
      }
      i32x4 lo, hi;
      lo.x = pack2(f0.x, f0.y); lo.y = pack2(f0.z, f0.w);
      lo.z = pack2(f1.x, f1.y); lo.w = pack2(f1.z, f1.w);
      hi.x = pack2(f2.x, f2.y); hi.y = pack2(f2.z, f2.w);
      hi.z = pack2(f3.x, f3.y); hi.w = pack2(f3.z, f3.w);
      *(i32x4*)(&As[sr * 72 + sc]) = lo;
      *(i32x4*)(&As[sr * 72 + sc + 8]) = hi;
    }
    // stage W (fp32 -> bf16)
    {
      const f32x4* sp = (const f32x4*)(Wrow + k0 + sc);
      f32x4 f0 = sp[0], f1 = sp[1], f2 = sp[2], f3 = sp[3];
      i32x4 lo, hi;
      lo.x = pack2(f0.x, f0.y); lo.y = pack2(f0.z, f0.w);
      lo.z = pack2(f1.x, f1.y); lo.w = pack2(f1.z, f1.w);
      hi.x = pack2(f2.x, f2.y); hi.y = pack2(f2.z, f2.w);
      hi.z = pack2(f3.x, f3.y); hi.w = pack2(f3.z, f3.w);
      *(i32x4*)(&Ws[sr * 72 + sc]) = lo;
      *(i32x4*)(&Ws[sr * 72 + sc + 8]) = hi;
    }
    __syncthreads();
#pragma unroll
    for (int ks = 0; ks < 64; ks += 32) {
      bf16x8 a0 = *(bf16x8*)(&As[(wm + frow) * 72 + ks + quad * 8]);
      bf16x8 a1 = *(bf16x8*)(&As[(wm + 16 + frow) * 72 + ks + quad * 8]);
      bf16x8 b0 = *(bf16x8*)(&Ws[(wn + frow) * 72 + ks + quad * 8]);
      bf16x8 b1 = *(bf16x8*)(&Ws[(wn + 16 + frow) * 72 + ks + quad * 8]);
      acc[0][0] = MFMA_BF16(a0, b0, acc[0][0], 0, 0, 0);
      acc[0][1] = MFMA_BF16(a0, b1, acc[0][1], 0, 0, 0);
      acc[1][0] = MFMA_BF16(a1, b0, acc[1][0], 0, 0, 0);
      acc[1][1] = MFMA_BF16(a1, b1, acc[1][1], 0, 0, 0);
    }
    __syncthreads();
  }
  const float* b1p = B1 + (size_t)e * I;
#pragma unroll
  for (int i = 0; i < 2; ++i) {
#pragma unroll
    for (int j = 0; j < 2; ++j) {
      int n = n0 + wn + j * 16 + frow;
      float bias = b1p[n];
#pragma unroll
      for (int reg = 0; reg < 4; ++reg) {
        int r = m0 + wm + i * 16 + quad * 4 + reg;
        if (r < PB) {
          float v = gelu_f(acc[i][j][reg] + bias);
          Hb[((size_t)e * PB + r) * I + n] = (unsigned short)f2bf_u(v);
        }
      }
    }
  }
}

// down: ACC[tok][H] += gather-scatter( Hb_e @ W2_e^T + b2_e )
__global__ __launch_bounds__(256) void k_moe_down_mfma(const unsigned short* __restrict__ Hb, int nTok,
                                                       const int* __restrict__ pairs, int PB,
                                                       const float* __restrict__ W2, const float* __restrict__ B2,
                                                       float* __restrict__ ACC) {
  int e = blockIdx.z;
  int n0 = blockIdx.x * 64, m0 = blockIdx.y * 64;
  __shared__ __align__(16) short As[64 * 72];
  __shared__ __align__(16) short Ws[64 * 72];
  __shared__ int tokLds[64];
  int t = threadIdx.x;
  if (t < 64) {
    int r = m0 + t;
    int tk = (r < PB) ? pairs[(size_t)e * PB + r] : 0;
    if ((unsigned)tk >= (unsigned)nTok) tk = 0;
    tokLds[t] = tk;
  }
  __syncthreads();
  int sr = t >> 2, sc = (t & 3) * 16;
  bool arow_ok = (m0 + sr) < PB;
  const unsigned short* Arow = Hb + ((size_t)e * PB + (m0 + sr)) * I;
  const float* Wrow = W2 + (size_t)e * H * I + (size_t)(n0 + sr) * I;
  int w = t >> 6, lane = t & 63;
  int wm = (w >> 1) * 32, wn = (w & 1) * 32;
  int frow = lane & 15, quad = lane >> 4;
  f32x4 acc[2][2] = {};
  for (int k0 = 0; k0 < I; k0 += 64) {
    // stage A (bf16 direct copy)
    {
      i32x4 lo = {}, hi = {};
      if (arow_ok) {
        const i32x4* sp = (const i32x4*)(Arow + k0 + sc);
        lo = sp[0]; hi = sp[1];
      }
      *(i32x4*)(&As[sr * 72 + sc]) = lo;
      *(i32x4*)(&As[sr * 72 + sc + 8]) = hi;
    }
    // stage W (fp32 -> bf16)
    {
      const f32x4* sp = (const f32x4*)(Wrow + k0 + sc);
      f32x4 f0 = sp[0], f1 = sp[1], f2 = sp[2], f3 = sp[3];
      i32x4 lo, hi;
      lo.x = pack2(f0.x, f0.y); lo.y = pack2(f0.z, f0.w);
      lo.z = pack2(f1.x, f1.y); lo.w = pack2(f1.z, f1.w);
      hi.x = pack2(f2.x, f2.y); hi.y = pack2(f2.z, f2.w);
      hi.z = pack2(f3.x, f3.y); hi.w = pack2(f3.z, f3.w);
      *(i32x4*)(&Ws[sr * 72 + sc]) = lo;
      *(i32x4*)(&Ws[sr * 72 + sc + 8]) = hi;
    }
    __syncthreads();
#pragma unroll
    for (int ks = 0; ks < 64; ks += 32) {
      bf16x8 a0 = *(bf16x8*)(&As[(wm + frow) * 72 + ks + quad * 8]);
      bf16x8 a1 = *(bf16x8*)(&As[(wm + 16 + frow) * 72 + ks + quad * 8]);
      bf16x8 b0 = *(bf16x8*)(&Ws[(wn + frow) * 72 + ks + quad * 8]);
      bf16x8 b1 = *(bf16x8*)(&Ws[(wn + 16 + frow) * 72 + ks + quad * 8]);
      acc[0][0] = MFMA_BF16(a0, b0, acc[0][0], 0, 0, 0);
      acc[0][1] = MFMA_BF16(a0, b1, acc[0][1], 0, 0, 0);
      acc[1][0] = MFMA_BF16(a1, b0, acc[1][0], 0, 0, 0);
      acc[1][1] = MFMA_BF16(a1, b1, acc[1][1], 0, 0, 0);
    }
    __syncthreads();
  }
  const float* b2p = B2 + (size_t)e * H;
#pragma unroll
  for (int i = 0; i < 2; ++i) {
#pragma unroll
    for (int j = 0; j < 2; ++j) {
      int n = n0 + wn + j * 16 + frow;
      float bias = b2p[n];
#pragma unroll
      for (int reg = 0; reg < 4; ++reg) {
        int r = m0 + wm + i * 16 + quad * 4 + reg;
        if (r < PB) {
          int tok = tokLds[wm + i * 16 + quad * 4 + reg];
          atomicAdd(&ACC[(size_t)tok * H + n], acc[i][j][reg] + bias);
        }
      }
    }
  }
}

// ---------------- final ----------------
__global__ __launch_bounds__(256) void k_final(const float* __restrict__ base, const float* __restrict__ acc,
                                               const int* __restrict__ cnt, float* __restrict__ out, int n) {
  int i = blockIdx.x * 256 + threadIdx.x;
  if (i >= n) return;
  int row = i >> 10;
  int c = cnt[row]; if (c < 1) c = 1;
  out[i] = base[i] + acc[i] / (float)c;
}

extern "C" void kernel_launch(void* const* d_in, const int* in_sizes, int n_in,
                              void* d_out, int out_size, void* d_ws, size_t ws_size,
                              hipStream_t stream) {
  float* out = (float*)d_out;
  dim3 blk(256);
  const int OUT_N = (int)(FQ + FIMG);
  int outN = out_size;

  static const int EXP[25] = {
    B * T * H, B * V * H, B * L * H,
    3 * H * H, 3 * H, H * H, H,
    3 * H * H, 3 * H, H * H, H,
    E * 2 * H, E, E * 2 * H, E,
    E * I * H, E * I, E * H * I, E * H,
    H, H, H, H, H, H
  };
  if (n_in != 25) { k_diag<<<dim3((outN + 255) / 256), blk, 0, stream>>>(out, outN, 40000.f); return; }
  for (int i = 0; i < 25; ++i)
    if (in_sizes[i] != EXP[i]) {
      k_diag<<<dim3((outN + 255) / 256), blk, 0, stream>>>(out, outN, 20000.f + 1000.f * i);
      return;
    }
  if (out_size != OUT_N) { k_diag<<<dim3((outN + 255) / 256), blk, 0, stream>>>(out, outN, 30000.f); return; }
  if (ws_size < WS_FLOATS * sizeof(float)) {
    k_diag<<<dim3((outN + 255) / 256), blk, 0, stream>>>(out, outN, 12345.f);
    return;
  }

  float* wsf = (float*)d_ws;
  float* Q = wsf + oQ;  float* XN = wsf + oXN;  float* AO = wsf + oAO;  float* IMG32 = wsf + oIMG;
  float* CTXI = wsf + oCTXI;  float* CTXT = wsf + oCTXT;
  float* PRT = wsf + oPRT;    float* PRI = wsf + oPRI;
  float* SW = wsf + oSW;
  int* FLAG = (int*)(wsf + oINT);
  int* PAIRS_T = FLAG + 1;
  int* PAIRS_I = PAIRS_T + E * PBT;
  int* CNT_T = PAIRS_I + E * PBI;
  int* CNT_I = CNT_T + B * T;
  float* QKV = wsf + oBIG;                       // attention phase
  unsigned short* HBu = (unsigned short*)(wsf + oBIG);  // MoE phase (QKV dead)

  k_detect<<<dim3(1), blk, 0, stream>>>(d_in[0], FLAG);

  // fused small-weight conversions (16 segments, prefix-contiguous in SW)
  {
    CvtTab tab;
    const int srcIdx[16] = {4, 6, 8, 10, 11, 12, 13, 14, 16, 18, 19, 20, 21, 22, 23, 24};
    const int starts[17] = {(int)sSA_B_IN, (int)sSA_B_OUT, (int)sCA_B_IN, (int)sCA_B_OUT,
                            (int)sGIW, (int)sGIB, (int)sGTW, (int)sGTB,
                            (int)sEB1, (int)sEB2,
                            (int)sLNQG, (int)sLNQB, (int)sLNCG, (int)sLNCB, (int)sLNFG, (int)sLNFB,
                            (int)SWN};
    for (int c = 0; c < 16; ++c) tab.src[c] = d_in[srcIdx[c]];
    for (int c = 0; c < 17; ++c) tab.start[c] = starts[c];
    k_cvt_multi<<<dim3(((int)SWN + 255) / 256), blk, 0, stream>>>(tab, SW, FLAG);
  }

  k_cvt2<<<dim3((int)(FQ / 256)), blk, 0, stream>>>(d_in[0], Q, (int)FQ, FLAG);
  k_cvt2<<<dim3((int)(FIMG / 256)), blk, 0, stream>>>(d_in[1], IMG32, (int)FIMG, FLAG);

  // ---- 1) self-attention ----
  k_ln<<<dim3(B * T), blk, 0, stream>>>(Q, SW + sLNQG, SW + sLNQB, XN);
  k_gemm_sp<false><<<dim3(3 * H / 64, B * T / 64), blk, 0, stream>>>(
      XN, H, d_in[3], 0, H, SW + sSA_B_IN, QKV, 3 * H, B * T, 3 * H, H, FLAG);
  k_attn_tile<<<dim3(T / 64, NH, B), blk, 0, stream>>>(QKV, 3 * H, QKV + H, 3 * H, QKV + 2 * H, 3 * H, AO, T, T);
  k_gemm_sp<true><<<dim3(H / 64, B * T / 64), blk, 0, stream>>>(
      AO, H, d_in[5], 0, H, SW + sSA_B_OUT, Q, H, B * T, H, H, FLAG);

  // ---- 2) cross-attention ----
  k_ln<<<dim3(B * T), blk, 0, stream>>>(Q, SW + sLNCG, SW + sLNCB, XN);
  k_gemm_sp<false><<<dim3(H / 64, B * T / 64), blk, 0, stream>>>(
      XN, H, d_in[7], 0, H, SW + sCA_B_IN, QKV, H, B * T, H, H, FLAG);
  k_gemm_sp<false><<<dim3(2 * H / 64, B * V / 64), blk, 0, stream>>>(
      IMG32, H, d_in[7], (size_t)H * H, H, SW + sCA_B_IN + H, QKV + FQ, 2 * H, B * V, 2 * H, H, FLAG);
  k_attn_tile<<<dim3(T / 64, NH, B), blk, 0, stream>>>(QKV, H, QKV + FQ, 2 * H, QKV + FQ + H, 2 * H, AO, T, V);
  k_gemm_sp<true><<<dim3(H / 64, B * T / 64), blk, 0, stream>>>(
      AO, H, d_in[9], 0, H, SW + sCA_B_OUT, Q, H, B * T, H, H, FLAG);

  // ---- 3) gating ----
  k_mean_f32<<<dim3((B * H) / 256), blk, 0, stream>>>(IMG32, CTXI, V);
  k_mean_in<<<dim3((B * H) / 256), blk, 0, stream>>>(d_in[2], CTXT, L, FLAG);
  k_gate<<<dim3(B * T), blk, 0, stream>>>(Q, CTXI, SW + sGTW, SW + sGTB, PRT, T);
  k_gate<<<dim3(B * V), blk, 0, stream>>>(IMG32, CTXT, SW + sGIW, SW + sGIB, PRI, V);
  k_zeroi<<<dim3((B * T + B * V + 255) / 256), blk, 0, stream>>>(CNT_T, B * T + B * V);

  // ---- 4) top-k for BOTH streams (one dispatch, wave-parallel, barrier-free) ----
  k_topk2<<<dim3(16), blk, 0, stream>>>(PRT, PRI, PAIRS_T, PAIRS_I, CNT_T, CNT_I);

  // ---- 5) text MoE (MFMA) ----
  k_ln<<<dim3(B * T), blk, 0, stream>>>(Q, SW + sLNFG, SW + sLNFB, XN);
  k_zerof<<<dim3((int)(FQ / 256)), blk, 0, stream>>>(AO, (int)FQ);
  k_moe_up_mfma<<<dim3(I / 64, PBT / 64, E), blk, 0, stream>>>(
      XN, B * T, PAIRS_T, PBT, (const float*)d_in[15], (const float*)d_in[16], HBu);
  k_moe_down_mfma<<<dim3(H / 64, PBT / 64, E), blk, 0, stream>>>(
      HBu, B * T, PAIRS_T, PBT, (const float*)d_in[17], (const float*)d_in[18], AO);
  k_final<<<dim3((int)(FQ / 256)), blk, 0, stream>>>(Q, AO, CNT_T, out, (int)FQ);

  // ---- 6) image MoE (MFMA) ----
  k_zerof<<<dim3((int)(FIMG / 256)), blk, 0, stream>>>(AO, (int)FIMG);
  k_moe_up_mfma<<<dim3(I / 64, (PBI + 63) / 64, E), blk, 0, stream>>>(
      IMG32, B * V, PAIRS_I, PBI, (const float*)d_in[15], (const float*)d_in[16], HBu);
  k_moe_down_mfma<<<dim3(H / 64, (PBI + 63) / 64, E), blk, 0, stream>>>(
      HBu, B * V, PAIRS_I, PBI, (const float*)d_in[17], (const float*)d_in[18], AO);
  k_final<<<dim3((int)(FIMG / 256)), blk, 0, stream>>>(IMG32, AO, CNT_I, out + FQ, (int)FIMG);
}

// Round 6
// 1364.214 us; speedup vs baseline: 2.7477x; 1.1689x over previous
//
#include <hip/hip_runtime.h>
#include <hip/hip_bf16.h>

using bf16 = __hip_bfloat16;

namespace {
constexpr int B = 4, T = 512, V = 576, L = 256, H = 1024, NH = 16, HD = 64, I = 4096, E = 8;
constexpr int KT = 80;          // int(1.25*512 + 7) // 8 = 80
constexpr int KI = 90;          // int(1.25*576 + 7) // 8 = 90
constexpr int PBT = B * KT;     // 320
constexpr int PBI = B * KI;     // 360
constexpr int MCH = 16;         // tokens per mean-partial chunk
constexpr int NCHI = V / MCH;   // 36
constexpr int NCHT = L / MCH;   // 16

constexpr size_t FQ   = (size_t)B * T * H;   // 2,097,152
constexpr size_t FIMG = (size_t)B * V * H;   // 2,359,296
constexpr size_t FQKV = FQ + (size_t)B * V * 2 * H;  // 6,815,744
constexpr size_t FHB  = (size_t)E * PBI * I;         // 11,796,480 (bf16 elems in MoE phase)

// small-weight (fp32-converted) region offsets (prefix-contiguous)
constexpr size_t sSA_B_IN = 0, sSA_B_OUT = 3072, sCA_B_IN = 4096, sCA_B_OUT = 7168;
constexpr size_t sGIW = 8192, sGIB = 24576, sGTW = 24584, sGTB = 40968;
constexpr size_t sEB1 = 40976, sEB2 = 73744;
constexpr size_t sLNQG = 81936, sLNQB = 82960, sLNCG = 83984, sLNCB = 85008, sLNFG = 86032, sLNFB = 87056;
constexpr size_t SWN = 88080;

// ws layout (float offsets)
constexpr size_t oQ = 0, oXN = oQ + FQ, oAO = oXN + FQ, oIMG = oAO + FIMG;
constexpr size_t oCTXI = oIMG + FIMG, oCTXT = oCTXI + (size_t)B * H;
constexpr size_t oPRT = oCTXT + (size_t)B * H, oPRI = oPRT + (size_t)B * T * E;
constexpr size_t oSW = oPRI + (size_t)B * V * E;
constexpr size_t oINT = oSW + SWN;                      // int region (flag + pairs + counts)
constexpr size_t oBIG = oINT + 16384;                   // QKV(f32) / HB(bf16) / mean-partials union
constexpr size_t WS_FLOATS = oBIG + (FQKV > FHB ? FQKV : FHB);
}

typedef __attribute__((ext_vector_type(8))) short bf16x8;
typedef __attribute__((ext_vector_type(4))) float f32x4;
typedef __attribute__((ext_vector_type(4))) int i32x4;

__device__ __forceinline__ float b2f(bf16 x) { return __bfloat162float(x); }

__device__ __forceinline__ float ldany(const void* p, int f32, size_t idx) {
  return f32 ? ((const float*)p)[idx] : b2f(((const bf16*)p)[idx]);
}

__device__ __forceinline__ unsigned int f2bf_u(float v) {   // RNE fp32->bf16 bits
  unsigned int u = __float_as_uint(v);
  u += 0x7FFFu + ((u >> 16) & 1u);
  return u >> 16;
}
__device__ __forceinline__ int pack2(float a, float b) {
  return (int)(f2bf_u(a) | (f2bf_u(b) << 16));
}

__device__ __forceinline__ float gelu_f(float x) {
  float x3 = x * x * x;
  return 0.5f * x * (1.f + tanhf(0.7978845608028654f * (x + 0.044715f * x3)));
}

// split one fp32 vec4 chunk x4 (16 floats) into bf16 hi/lo words
__device__ __forceinline__ void split16(const f32x4* __restrict__ sp,
                                        short* __restrict__ hiDst, short* __restrict__ loDst) {
  int hw[8], lw[8];
#pragma unroll
  for (int u = 0; u < 4; ++u) {
    f32x4 v = sp[u];
    unsigned h0 = f2bf_u(v.x), h1 = f2bf_u(v.y), h2 = f2bf_u(v.z), h3 = f2bf_u(v.w);
    float r0 = v.x - __uint_as_float(h0 << 16);
    float r1 = v.y - __uint_as_float(h1 << 16);
    float r2 = v.z - __uint_as_float(h2 << 16);
    float r3 = v.w - __uint_as_float(h3 << 16);
    hw[u * 2 + 0] = (int)(h0 | (h1 << 16));
    hw[u * 2 + 1] = (int)(h2 | (h3 << 16));
    lw[u * 2 + 0] = pack2(r0, r1);
    lw[u * 2 + 1] = pack2(r2, r3);
  }
  ((i32x4*)hiDst)[0] = *(i32x4*)&hw[0];
  ((i32x4*)hiDst)[1] = *(i32x4*)&hw[4];
  ((i32x4*)loDst)[0] = *(i32x4*)&lw[0];
  ((i32x4*)loDst)[1] = *(i32x4*)&lw[4];
}

// ---------------- dtype probe ----------------
__global__ __launch_bounds__(256) void k_detect(const void* __restrict__ q, int* __restrict__ flag) {
  __shared__ int cnt;
  if (threadIdx.x == 0) cnt = 0;
  __syncthreads();
  int local = 0;
  for (int i = threadIdx.x; i < 65536; i += 256) {
    float v = b2f(((const bf16*)q)[i]);
    if (!(fabsf(v) < 1e4f)) local++;
  }
  atomicAdd(&cnt, local);
  __syncthreads();
  if (threadIdx.x == 0) *flag = (cnt > 64) ? 1 : 0;
}

__global__ __launch_bounds__(256) void k_cvt2(const void* __restrict__ in, float* __restrict__ out,
                                              int n, const int* __restrict__ flag) {
  int f32 = *flag;
  int i = blockIdx.x * 256 + threadIdx.x;
  if (i < n) out[i] = ldany(in, f32, (size_t)i);
}

// fused 16-segment small-weight conversion (segments are prefix-contiguous in dst)
struct CvtTab { const void* src[16]; int start[17]; };
__global__ __launch_bounds__(256) void k_cvt_multi(CvtTab tab, float* __restrict__ out,
                                                   const int* __restrict__ flag) {
  int f32 = *flag;
  int i = blockIdx.x * 256 + threadIdx.x;
  if (i >= (int)SWN) return;
  int lo = 0, hi = 15;
  while (lo < hi) { int mid = (lo + hi + 1) >> 1; if (i >= tab.start[mid]) lo = mid; else hi = mid - 1; }
  out[i] = ldany(tab.src[lo], f32, (size_t)(i - tab.start[lo]));
}

__global__ __launch_bounds__(256) void k_zerof(float* __restrict__ p, int n) {
  int i = blockIdx.x * 256 + threadIdx.x;
  if (i < n) p[i] = 0.f;
}
__global__ __launch_bounds__(256) void k_zeroi(int* __restrict__ p, int n) {
  int i = blockIdx.x * 256 + threadIdx.x;
  if (i < n) p[i] = 0;
}
__global__ __launch_bounds__(256) void k_diag(float* __restrict__ out, int n, float code) {
  int i = blockIdx.x * 256 + threadIdx.x;
  if (i < n) out[i] = (i == 0 ? code : 0.f);
}

// ---------------- LayerNorm ----------------
__global__ __launch_bounds__(256) void k_ln(const float* __restrict__ X,
                                            const float* __restrict__ g, const float* __restrict__ bta,
                                            float* __restrict__ Y) {
  int row = blockIdx.x;
  const float* x = X + (size_t)row * H;
  float s = 0.f, ss = 0.f;
  for (int j = threadIdx.x; j < H; j += 256) { float v = x[j]; s += v; ss += v * v; }
#pragma unroll
  for (int off = 32; off; off >>= 1) { s += __shfl_xor(s, off); ss += __shfl_xor(ss, off); }
  __shared__ float ls[4], lss[4];
  __shared__ float mean_s, inv_s;
  int w = threadIdx.x >> 6, lane = threadIdx.x & 63;
  if (lane == 0) { ls[w] = s; lss[w] = ss; }
  __syncthreads();
  if (threadIdx.x == 0) {
    float S1 = ls[0] + ls[1] + ls[2] + ls[3];
    float S2 = lss[0] + lss[1] + lss[2] + lss[3];
    float m = S1 / (float)H;
    float var = S2 / (float)H - m * m;
    mean_s = m;
    inv_s = 1.f / sqrtf(var + 1e-5f);
  }
  __syncthreads();
  float m = mean_s, inv = inv_s;
  float* y = Y + (size_t)row * H;
  for (int j = threadIdx.x; j < H; j += 256)
    y[j] = (x[j] - m) * inv * g[j] + bta[j];
}

#define MFMA_BF16 __builtin_amdgcn_mfma_f32_16x16x32_bf16

// ---------------- split-bf16 MFMA GEMM (attention path, ~fp32 precision) ----------------
// C[m][n] = sum_k A[m][k] * W[n][k] + bias[n]  (optionally += C)
// Each fp32 operand split as hi(bf16) + lo(bf16); product = hh + hl + lh via 3 MFMA,
// fp32 accumulation. Dropped lo*lo term ~2^-18 relative. 64x64 tile, BK=64,
// 4 waves of 32x32 (2x2 16x16x32 frags). LDS row = [hi 64 | lo 64 | pad 8] bf16.
template <bool ADD>
__global__ __launch_bounds__(256) void k_gemm_sp(const float* __restrict__ A, int lda,
                                                 const void* __restrict__ W, size_t wOff, int ldw,
                                                 const float* __restrict__ bias,
                                                 float* __restrict__ C, int ldc,
                                                 int M, int N, int K, const int* __restrict__ flag) {
  __shared__ __align__(16) short As[64 * 136];
  __shared__ __align__(16) short Ws[64 * 136];
  int f32 = *flag;
  int n0 = blockIdx.x * 64, m0 = blockIdx.y * 64;
  int t = threadIdx.x;
  int sr = t >> 2, sc = (t & 3) * 16;
  const float* Arow = A + (size_t)(m0 + sr) * lda + sc;
  const float* WrowF = (const float*)W + wOff + (size_t)(n0 + sr) * ldw + sc;
  const bf16*  WrowH = (const bf16*)W + wOff + (size_t)(n0 + sr) * ldw + sc;
  int w = t >> 6, lane = t & 63;
  int wm = (w >> 1) * 32, wn = (w & 1) * 32;
  int frow = lane & 15, quad = lane >> 4;
  f32x4 acc[2][2] = {};
  for (int k0 = 0; k0 < K; k0 += 64) {
    // stage A (fp32 -> hi/lo bf16)
    split16((const f32x4*)(Arow + k0), &As[sr * 136 + sc], &As[sr * 136 + 64 + sc]);
    // stage W (fp32 fast path -> hi/lo; bf16 fallback -> hi only, lo = 0)
    if (f32) {
      split16((const f32x4*)(WrowF + k0), &Ws[sr * 136 + sc], &Ws[sr * 136 + 64 + sc]);
    } else {
      const i32x4* sp = (const i32x4*)(WrowH + k0);
      ((i32x4*)&Ws[sr * 136 + sc])[0] = sp[0];
      ((i32x4*)&Ws[sr * 136 + sc])[1] = sp[1];
      i32x4 z = {};
      ((i32x4*)&Ws[sr * 136 + 64 + sc])[0] = z;
      ((i32x4*)&Ws[sr * 136 + 64 + sc])[1] = z;
    }
    __syncthreads();
#pragma unroll
    for (int ks = 0; ks < 64; ks += 32) {
      bf16x8 a0h = *(bf16x8*)(&As[(wm + frow) * 136 + ks + quad * 8]);
      bf16x8 a1h = *(bf16x8*)(&As[(wm + 16 + frow) * 136 + ks + quad * 8]);
      bf16x8 a0l = *(bf16x8*)(&As[(wm + frow) * 136 + 64 + ks + quad * 8]);
      bf16x8 a1l = *(bf16x8*)(&As[(wm + 16 + frow) * 136 + 64 + ks + quad * 8]);
      bf16x8 b0h = *(bf16x8*)(&Ws[(wn + frow) * 136 + ks + quad * 8]);
      bf16x8 b1h = *(bf16x8*)(&Ws[(wn + 16 + frow) * 136 + ks + quad * 8]);
      bf16x8 b0l = *(bf16x8*)(&Ws[(wn + frow) * 136 + 64 + ks + quad * 8]);
      bf16x8 b1l = *(bf16x8*)(&Ws[(wn + 16 + frow) * 136 + 64 + ks + quad * 8]);
      acc[0][0] = MFMA_BF16(a0h, b0h, acc[0][0], 0, 0, 0);
      acc[0][1] = MFMA_BF16(a0h, b1h, acc[0][1], 0, 0, 0);
      acc[1][0] = MFMA_BF16(a1h, b0h, acc[1][0], 0, 0, 0);
      acc[1][1] = MFMA_BF16(a1h, b1h, acc[1][1], 0, 0, 0);
      acc[0][0] = MFMA_BF16(a0h, b0l, acc[0][0], 0, 0, 0);
      acc[0][1] = MFMA_BF16(a0h, b1l, acc[0][1], 0, 0, 0);
      acc[1][0] = MFMA_BF16(a1h, b0l, acc[1][0], 0, 0, 0);
      acc[1][1] = MFMA_BF16(a1h, b1l, acc[1][1], 0, 0, 0);
      acc[0][0] = MFMA_BF16(a0l, b0h, acc[0][0], 0, 0, 0);
      acc[0][1] = MFMA_BF16(a0l, b1h, acc[0][1], 0, 0, 0);
      acc[1][0] = MFMA_BF16(a1l, b0h, acc[1][0], 0, 0, 0);
      acc[1][1] = MFMA_BF16(a1l, b1h, acc[1][1], 0, 0, 0);
    }
    __syncthreads();
  }
#pragma unroll
  for (int i = 0; i < 2; ++i)
#pragma unroll
    for (int j = 0; j < 2; ++j) {
      int n = n0 + wn + j * 16 + frow;
      float bv = bias[n];
#pragma unroll
      for (int reg = 0; reg < 4; ++reg) {
        int gm = m0 + wm + i * 16 + quad * 4 + reg;
        float v = acc[i][j][reg] + bv;
        size_t o = (size_t)gm * ldc + n;
        if (ADD) v += C[o];
        C[o] = v;
      }
    }
}

// ---------------- flash-tiled attention (fp32, 64-query tile per block) ----------------
__global__ __launch_bounds__(256) void k_attn_tile(const float* __restrict__ Qb, int qStride,
                                                   const float* __restrict__ Kb, int kStride,
                                                   const float* __restrict__ Vb, int vStride,
                                                   float* __restrict__ Ob, int Tq, int Tk) {
  int h = blockIdx.y, b = blockIdx.z;
  int q0 = blockIdx.x * 64;
  __shared__ float Qt[64][68];   // [d][q]
  __shared__ float KV[64][68];   // S phase: [d][k]; PV phase: [k][d]
  __shared__ float Ps[64][68];   // [q][k]
  int t = threadIdx.x;
  int tm = t >> 4, tn = t & 15;
  int sr = t >> 2, c0 = (t & 3) * 16;   // staging: row sr (0..63), 16-float chunk c0

  // stage Q transposed (once)
  {
    const float* src = Qb + ((size_t)(b * Tq + q0 + sr)) * qStride + h * HD + c0;
#pragma unroll
    for (int u = 0; u < 4; ++u) {
      f32x4 v = *(const f32x4*)(src + u * 4);
      Qt[c0 + u * 4 + 0][sr] = v.x;
      Qt[c0 + u * 4 + 1][sr] = v.y;
      Qt[c0 + u * 4 + 2][sr] = v.z;
      Qt[c0 + u * 4 + 3][sr] = v.w;
    }
  }

  float m[4], l[4];
  f32x4 oacc[4] = {};
#pragma unroll
  for (int i = 0; i < 4; ++i) { m[i] = -1e30f; l[i] = 0.f; }

  for (int k0 = 0; k0 < Tk; k0 += 64) {
    // stage K tile transposed into KV[d][k]
    {
      const float* src = Kb + ((size_t)(b * Tk + k0 + sr)) * kStride + h * HD + c0;
#pragma unroll
      for (int u = 0; u < 4; ++u) {
        f32x4 v = *(const f32x4*)(src + u * 4);
        KV[c0 + u * 4 + 0][sr] = v.x;
        KV[c0 + u * 4 + 1][sr] = v.y;
        KV[c0 + u * 4 + 2][sr] = v.z;
        KV[c0 + u * 4 + 3][sr] = v.w;
      }
    }
    __syncthreads();
    // S = Q.K^T, thread tile 4x4
    float sacc[4][4] = {};
#pragma unroll 8
    for (int d = 0; d < 64; ++d) {
      f32x4 a = *(const f32x4*)(&Qt[d][tm * 4]);
      f32x4 bb = *(const f32x4*)(&KV[d][tn * 4]);
#pragma unroll
      for (int i = 0; i < 4; ++i)
#pragma unroll
        for (int j = 0; j < 4; ++j) sacc[i][j] = fmaf(a[i], bb[j], sacc[i][j]);
    }
    __syncthreads();   // everyone done reading K from KV
    // stage V tile natural into KV[k][d]
    {
      const float* src = Vb + ((size_t)(b * Tk + k0 + sr)) * vStride + h * HD + c0;
#pragma unroll
      for (int u = 0; u < 4; ++u)
        *(f32x4*)(&KV[sr][c0 + u * 4]) = *(const f32x4*)(src + u * 4);
    }
    // online softmax in registers
#pragma unroll
    for (int i = 0; i < 4; ++i) {
      float rm = -1e30f;
#pragma unroll
      for (int j = 0; j < 4; ++j) { sacc[i][j] *= 0.125f; rm = fmaxf(rm, sacc[i][j]); }
#pragma unroll
      for (int off = 1; off < 16; off <<= 1) rm = fmaxf(rm, __shfl_xor(rm, off));
      float mnew = fmaxf(m[i], rm);
      float rs = 0.f;
#pragma unroll
      for (int j = 0; j < 4; ++j) { float p = __expf(sacc[i][j] - mnew); sacc[i][j] = p; rs += p; }
#pragma unroll
      for (int off = 1; off < 16; off <<= 1) rs += __shfl_xor(rs, off);
      float scl = __expf(m[i] - mnew);
      l[i] = l[i] * scl + rs;
      m[i] = mnew;
#pragma unroll
      for (int j = 0; j < 4; ++j) oacc[i][j] *= scl;
      f32x4 pv;
      pv.x = sacc[i][0]; pv.y = sacc[i][1]; pv.z = sacc[i][2]; pv.w = sacc[i][3];
      *(f32x4*)(&Ps[tm * 4 + i][tn * 4]) = pv;
    }
    __syncthreads();   // Ps written, V staged
    // O += P @ V
#pragma unroll 4
    for (int kk = 0; kk < 64; kk += 4) {
      f32x4 a[4];
#pragma unroll
      for (int i = 0; i < 4; ++i) a[i] = *(const f32x4*)(&Ps[tm * 4 + i][kk]);
#pragma unroll
      for (int u = 0; u < 4; ++u) {
        f32x4 vv = *(const f32x4*)(&KV[kk + u][tn * 4]);
#pragma unroll
        for (int i = 0; i < 4; ++i)
#pragma unroll
          for (int j = 0; j < 4; ++j) oacc[i][j] = fmaf(a[i][u], vv[j], oacc[i][j]);
      }
    }
    __syncthreads();   // done reading KV(V)/Ps before next tile restages
  }
#pragma unroll
  for (int i = 0; i < 4; ++i) {
    float inv = 1.f / l[i];
    f32x4 r;
#pragma unroll
    for (int j = 0; j < 4; ++j) r[j] = oacc[i][j] * inv;
    *(f32x4*)(Ob + ((size_t)(b * Tq + q0 + tm * 4 + i)) * H + h * HD + tn * 4) = r;
  }
}

// ---------------- parallel two-stage means (image + text fused, deterministic) ----------------
// Stage 1: one block per (batch, 16-token chunk); thread owns 4 columns (float4),
// sums 16 coalesced rows, writes partial [ch][b][H] into scratch (dead QKV region).
// Stage 2: 8192 threads reduce chunks (L2-resident) and divide by S.
__global__ __launch_bounds__(256) void k_mean_part(const float* __restrict__ IMG,
                                                   const void* __restrict__ TXT,
                                                   const int* __restrict__ flag,
                                                   float* __restrict__ part) {
  int blk = blockIdx.x, t = threadIdx.x;
  if (blk < B * NCHI) {
    int b = blk / NCHI, ch = blk - b * NCHI;
    const float* base = IMG + ((size_t)(b * V + ch * MCH)) * H + t * 4;
    f32x4 s = {};
#pragma unroll
    for (int r = 0; r < MCH; ++r) s += *(const f32x4*)(base + (size_t)r * H);
    *(f32x4*)(part + ((size_t)ch * B + b) * H + t * 4) = s;
  } else {
    int bi = blk - B * NCHI;
    int b = bi / NCHT, ch = bi - b * NCHT;
    int f32 = *flag;
    size_t base = ((size_t)(b * L + ch * MCH)) * H + t * 4;
    f32x4 s = {};
    for (int r = 0; r < MCH; ++r) {
      size_t o = base + (size_t)r * H;
      s.x += ldany(TXT, f32, o + 0);
      s.y += ldany(TXT, f32, o + 1);
      s.z += ldany(TXT, f32, o + 2);
      s.w += ldany(TXT, f32, o + 3);
    }
    *(f32x4*)(part + ((size_t)(NCHI * B) + (size_t)ch * B + b) * H + t * 4) = s;
  }
}

__global__ __launch_bounds__(256) void k_mean_fin(const float* __restrict__ part,
                                                  float* __restrict__ CTXI, float* __restrict__ CTXT) {
  int i = blockIdx.x * 256 + threadIdx.x;     // grid covers 2*B*H
  if (i < B * H) {
    int b = i >> 10, d = i & (H - 1);
    float s = 0.f;
    for (int ch = 0; ch < NCHI; ++ch) s += part[((size_t)ch * B + b) * H + d];
    CTXI[i] = s / (float)V;
  } else {
    int j = i - B * H;
    int b = j >> 10, d = j & (H - 1);
    float s = 0.f;
    for (int ch = 0; ch < NCHT; ++ch) s += part[((size_t)(NCHI * B) + (size_t)ch * B + b) * H + d];
    CTXT[j] = s / (float)L;
  }
}

// ---------------- gate ----------------
__global__ __launch_bounds__(256) void k_gate(const float* __restrict__ X, const float* __restrict__ ctx,
                                              const float* __restrict__ Wg, const float* __restrict__ bg,
                                              float* __restrict__ probs, int S) {
  int row = blockIdx.x;
  int b = row / S;
  const float* xr = X + (size_t)row * H;
  const float* cx = ctx + (size_t)b * H;
  float p[E] = {};
  for (int j = threadIdx.x; j < 2 * H; j += 256) {
    float xv = (j < H) ? xr[j] : cx[j - H];
#pragma unroll
    for (int e = 0; e < E; ++e) p[e] += xv * Wg[(size_t)e * 2 * H + j];
  }
#pragma unroll
  for (int e = 0; e < E; ++e)
#pragma unroll
    for (int off = 32; off; off >>= 1) p[e] += __shfl_xor(p[e], off);
  __shared__ float gl[4][E];
  int w = threadIdx.x >> 6, lane = threadIdx.x & 63;
  if (lane == 0)
#pragma unroll
    for (int e = 0; e < E; ++e) gl[w][e] = p[e];
  __syncthreads();
  if (threadIdx.x == 0) {
    float lg[E], mx = -1e30f;
    for (int e = 0; e < E; ++e) {
      lg[e] = gl[0][e] + gl[1][e] + gl[2][e] + gl[3][e] + bg[e];
      mx = fmaxf(mx, lg[e]);
    }
    float ssum = 0.f;
    for (int e = 0; e < E; ++e) { lg[e] = __expf(lg[e] - mx); ssum += lg[e]; }
    float inv = 1.f / ssum;
    for (int e = 0; e < E; ++e) probs[(size_t)row * E + e] = lg[e] * inv;
  }
}

// ---------------- fused wave-parallel top-k (both streams, barrier-free) ----------------
__global__ __launch_bounds__(256) void k_topk2(const float* __restrict__ probsT, const float* __restrict__ probsI,
                                               int* __restrict__ pairsT, int* __restrict__ pairsI,
                                               int* __restrict__ cntT, int* __restrict__ cntI) {
  __shared__ float vals[4][640];
  int wv = threadIdx.x >> 6, lane = threadIdx.x & 63;
  int p = blockIdx.x * 4 + wv;             // 0..63
  int st = p >> 5, idx = p & 31;
  int e = idx >> 2, b = idx & 3;
  const float* probs = st ? probsI : probsT;
  int S  = st ? V : T;
  int k  = st ? KI : KT;
  int* pairs = st ? pairsI : pairsT;
  int* cnt   = st ? cntI : cntT;
  int PB = st ? PBI : PBT;
  float* v = vals[wv];
  for (int j = lane; j < S; j += 64) {
    float x = probs[((size_t)b * S + j) * E + e];
    v[j] = (x == x) ? x : -1e30f;
  }
  for (int it = 0; it < k; ++it) {
    float best = -2e30f; int besti = 0x7FFFFFFF;
    for (int j = lane; j < S; j += 64) {
      float x = v[j];
      if (x > best || (x == best && j < besti)) { best = x; besti = j; }
    }
#pragma unroll
    for (int off = 1; off < 64; off <<= 1) {
      float ob = __shfl_xor(best, off);
      int   oi = __shfl_xor(besti, off);
      if (ob > best || (ob == best && oi < besti)) { best = ob; besti = oi; }
    }
    int sidx = besti;
    if ((unsigned)sidx >= (unsigned)S) sidx = 0;
    if (lane == 0) {
      pairs[e * PB + b * k + it] = b * S + sidx;
      atomicAdd(&cnt[b * S + sidx], 1);
    }
    v[sidx] = -1e30f;   // all lanes, same addr, same value
  }
}

// ================= MFMA MoE =================
// 64x64 tile, 4 waves each computing 32x32 via 2x2 mfma_f32_16x16x32_bf16, BK=64.
// LDS row stride 72 bf16 (144 B): conflict-free b128 frag reads + int4 staging writes.

// up: Hb[e*PB+r][I] (bf16) = gelu(gather(X)[r] @ W1_e^T + b1_e)
__global__ __launch_bounds__(256) void k_moe_up_mfma(const float* __restrict__ X, int nTok,
                                                     const int* __restrict__ pairs, int PB,
                                                     const float* __restrict__ W1, const float* __restrict__ B1,
                                                     unsigned short* __restrict__ Hb) {
  int e = blockIdx.z;
  int n0 = blockIdx.x * 64, m0 = blockIdx.y * 64;
  __shared__ __align__(16) short As[64 * 72];
  __shared__ __align__(16) short Ws[64 * 72];
  __shared__ int rowIdx[64];
  int t = threadIdx.x;
  if (t < 64) {
    int r = m0 + t;
    int ri = (r < PB) ? pairs[(size_t)e * PB + r] : -1;
    if ((unsigned)ri >= (unsigned)nTok) ri = -1;
    rowIdx[t] = ri;
  }
  __syncthreads();
  int sr = t >> 2, sc = (t & 3) * 16;
  const float* Wrow = W1 + (size_t)e * I * H + (size_t)(n0 + sr) * H;
  int ri = rowIdx[sr];
  const float* Xrow = (ri >= 0) ? X + (size_t)ri * H : nullptr;
  int w = t >> 6, lane = t & 63;
  int wm = (w >> 1) * 32, wn = (w & 1) * 32;
  int frow = lane & 15, quad = lane >> 4;
  f32x4 acc[2][2] = {};
  for (int k0 = 0; k0 < H; k0 += 64) {
    // stage A (gathered fp32 -> bf16)
    {
      f32x4 f0 = {}, f1 = {}, f2 = {}, f3 = {};
      if (Xrow) {
        const f32x4* sp = (const f32x4*)(Xrow + k0 + sc);
        f0 = sp[0]; f1 = sp[1]; f2 = sp[2]; f3 = sp[3];
      }
      i32x4 lo, hi;
      lo.x = pack2(f0.x, f0.y); lo.y = pack2(f0.z, f0.w);
      lo.z = pack2(f1.x, f1.y); lo.w = pack2(f1.z, f1.w);
      hi.x = pack2(f2.x, f2.y); hi.y = pack2(f2.z, f2.w);
      hi.z = pack2(f3.x, f3.y); hi.w = pack2(f3.z, f3.w);
      *(i32x4*)(&As[sr * 72 + sc]) = lo;
      *(i32x4*)(&As[sr * 72 + sc + 8]) = hi;
    }
    // stage W (fp32 -> bf16)
    {
      const f32x4* sp = (const f32x4*)(Wrow + k0 + sc);
      f32x4 f0 = sp[0], f1 = sp[1], f2 = sp[2], f3 = sp[3];
      i32x4 lo, hi;
      lo.x = pack2(f0.x, f0.y); lo.y = pack2(f0.z, f0.w);
      lo.z = pack2(f1.x, f1.y); lo.w = pack2(f1.z, f1.w);
      hi.x = pack2(f2.x, f2.y); hi.y = pack2(f2.z, f2.w);
      hi.z = pack2(f3.x, f3.y); hi.w = pack2(f3.z, f3.w);
      *(i32x4*)(&Ws[sr * 72 + sc]) = lo;
      *(i32x4*)(&Ws[sr * 72 + sc + 8]) = hi;
    }
    __syncthreads();
#pragma unroll
    for (int ks = 0; ks < 64; ks += 32) {
      bf16x8 a0 = *(bf16x8*)(&As[(wm + frow) * 72 + ks + quad * 8]);
      bf16x8 a1 = *(bf16x8*)(&As[(wm + 16 + frow) * 72 + ks + quad * 8]);
      bf16x8 b0 = *(bf16x8*)(&Ws[(wn + frow) * 72 + ks + quad * 8]);
      bf16x8 b1 = *(bf16x8*)(&Ws[(wn + 16 + frow) * 72 + ks + quad * 8]);
      acc[0][0] = MFMA_BF16(a0, b0, acc[0][0], 0, 0, 0);
      acc[0][1] = MFMA_BF16(a0, b1, acc[0][1], 0, 0, 0);
      acc[1][0] = MFMA_BF16(a1, b0, acc[1][0], 0, 0, 0);
      acc[1][1] = MFMA_BF16(a1, b1, acc[1][1], 0, 0, 0);
    }
    __syncthreads();
  }
  const float* b1p = B1 + (size_t)e * I;
#pragma unroll
  for (int i = 0; i < 2; ++i) {
#pragma unroll
    for (int j = 0; j < 2; ++j) {
      int n = n0 + wn + j * 16 + frow;
      float bias = b1p[n];
#pragma unroll
      for (int reg = 0; reg < 4; ++reg) {
        int r = m0 + wm + i * 16 + quad * 4 + reg;
        if (r < PB) {
          float v = gelu_f(acc[i][j][reg] + bias);
          Hb[((size_t)e * PB + r) * I + n] = (unsigned short)f2bf_u(v);
        }
      }
    }
  }
}

// down: ACC[tok][H] += gather-scatter( Hb_e @ W2_e^T + b2_e )
__global__ __launch_bounds__(256) void k_moe_down_mfma(const unsigned short* __restrict__ Hb, int nTok,
                                                       const int* __restrict__ pairs, int PB,
                                                       const float* __restrict__ W2, const float* __restrict__ B2,
                                                       float* __restrict__ ACC) {
  int e = blockIdx.z;
  int n0 = blockIdx.x * 64, m0 = blockIdx.y * 64;
  __shared__ __align__(16) short As[64 * 72];
  __shared__ __align__(16) short Ws[64 * 72];
  __shared__ int tokLds[64];
  int t = threadIdx.x;
  if (t < 64) {
    int r = m0 + t;
    int tk = (r < PB) ? pairs[(size_t)e * PB + r] : 0;
    if ((unsigned)tk >= (unsigned)nTok) tk = 0;
    tokLds[t] = tk;
  }
  __syncthreads();
  int sr = t >> 2, sc = (t & 3) * 16;
  bool arow_ok = (m0 + sr) < PB;
  const unsigned short* Arow = Hb + ((size_t)e * PB + (m0 + sr)) * I;
  const float* Wrow = W2 + (size_t)e * H * I + (size_t)(n0 + sr) * I;
  int w = t >> 6, lane = t & 63;
  int wm = (w >> 1) * 32, wn = (w & 1) * 32;
  int frow = lane & 15, quad = lane >> 4;
  f32x4 acc[2][2] = {};
  for (int k0 = 0; k0 < I; k0 += 64) {
    // stage A (bf16 direct copy)
    {
      i32x4 lo = {}, hi = {};
      if (arow_ok) {
        const i32x4* sp = (const i32x4*)(Arow + k0 + sc);
        lo = sp[0]; hi = sp[1];
      }
      *(i32x4*)(&As[sr * 72 + sc]) = lo;
      *(i32x4*)(&As[sr * 72 + sc + 8]) = hi;
    }
    // stage W (fp32 -> bf16)
    {
      const f32x4* sp = (const f32x4*)(Wrow + k0 + sc);
      f32x4 f0 = sp[0], f1 = sp[1], f2 = sp[2], f3 = sp[3];
      i32x4 lo, hi;
      lo.x = pack2(f0.x, f0.y); lo.y = pack2(f0.z, f0.w);
      lo.z = pack2(f1.x, f1.y); lo.w = pack2(f1.z, f1.w);
      hi.x = pack2(f2.x, f2.y); hi.y = pack2(f2.z, f2.w);
      hi.z = pack2(f3.x, f3.y); hi.w = pack2(f3.z, f3.w);
      *(i32x4*)(&Ws[sr * 72 + sc]) = lo;
      *(i32x4*)(&Ws[sr * 72 + sc + 8]) = hi;
    }
    __syncthreads();
#pragma unroll
    for (int ks = 0; ks < 64; ks += 32) {
      bf16x8 a0 = *(bf16x8*)(&As[(wm + frow) * 72 + ks + quad * 8]);
      bf16x8 a1 = *(bf16x8*)(&As[(wm + 16 + frow) * 72 + ks + quad * 8]);
      bf16x8 b0 = *(bf16x8*)(&Ws[(wn + frow) * 72 + ks + quad * 8]);
      bf16x8 b1 = *(bf16x8*)(&Ws[(wn + 16 + frow) * 72 + ks + quad * 8]);
      acc[0][0] = MFMA_BF16(a0, b0, acc[0][0], 0, 0, 0);
      acc[0][1] = MFMA_BF16(a0, b1, acc[0][1], 0, 0, 0);
      acc[1][0] = MFMA_BF16(a1, b0, acc[1][0], 0, 0, 0);
      acc[1][1] = MFMA_BF16(a1, b1, acc[1][1], 0, 0, 0);
    }
    __syncthreads();
  }
  const float* b2p = B2 + (size_t)e * H;
#pragma unroll
  for (int i = 0; i < 2; ++i) {
#pragma unroll
    for (int j = 0; j < 2; ++j) {
      int n = n0 + wn + j * 16 + frow;
      float bias = b2p[n];
#pragma unroll
      for (int reg = 0; reg < 4; ++reg) {
        int r = m0 + wm + i * 16 + quad * 4 + reg;
        if (r < PB) {
          int tok = tokLds[wm + i * 16 + quad * 4 + reg];
          atomicAdd(&ACC[(size_t)tok * H + n], acc[i][j][reg] + bias);
        }
      }
    }
  }
}

// ---------------- final ----------------
__global__ __launch_bounds__(256) void k_final(const float* __restrict__ base, const float* __restrict__ acc,
                                               const int* __restrict__ cnt, float* __restrict__ out, int n) {
  int i = blockIdx.x * 256 + threadIdx.x;
  if (i >= n) return;
  int row = i >> 10;
  int c = cnt[row]; if (c < 1) c = 1;
  out[i] = base[i] + acc[i] / (float)c;
}

extern "C" void kernel_launch(void* const* d_in, const int* in_sizes, int n_in,
                              void* d_out, int out_size, void* d_ws, size_t ws_size,
                              hipStream_t stream) {
  float* out = (float*)d_out;
  dim3 blk(256);
  const int OUT_N = (int)(FQ + FIMG);
  int outN = out_size;

  static const int EXP[25] = {
    B * T * H, B * V * H, B * L * H,
    3 * H * H, 3 * H, H * H, H,
    3 * H * H, 3 * H, H * H, H,
    E * 2 * H, E, E * 2 * H, E,
    E * I * H, E * I, E * H * I, E * H,
    H, H, H, H, H, H
  };
  if (n_in != 25) { k_diag<<<dim3((outN + 255) / 256), blk, 0, stream>>>(out, outN, 40000.f); return; }
  for (int i = 0; i < 25; ++i)
    if (in_sizes[i] != EXP[i]) {
      k_diag<<<dim3((outN + 255) / 256), blk, 0, stream>>>(out, outN, 20000.f + 1000.f * i);
      return;
    }
  if (out_size != OUT_N) { k_diag<<<dim3((outN + 255) / 256), blk, 0, stream>>>(out, outN, 30000.f); return; }
  if (ws_size < WS_FLOATS * sizeof(float)) {
    k_diag<<<dim3((outN + 255) / 256), blk, 0, stream>>>(out, outN, 12345.f);
    return;
  }

  float* wsf = (float*)d_ws;
  float* Q = wsf + oQ;  float* XN = wsf + oXN;  float* AO = wsf + oAO;  float* IMG32 = wsf + oIMG;
  float* CTXI = wsf + oCTXI;  float* CTXT = wsf + oCTXT;
  float* PRT = wsf + oPRT;    float* PRI = wsf + oPRI;
  float* SW = wsf + oSW;
  int* FLAG = (int*)(wsf + oINT);
  int* PAIRS_T = FLAG + 1;
  int* PAIRS_I = PAIRS_T + E * PBT;
  int* CNT_T = PAIRS_I + E * PBI;
  int* CNT_I = CNT_T + B * T;
  float* QKV = wsf + oBIG;                       // attention phase
  float* PART = wsf + oBIG;                      // mean partials (QKV dead by then)
  unsigned short* HBu = (unsigned short*)(wsf + oBIG);  // MoE phase (QKV dead)

  k_detect<<<dim3(1), blk, 0, stream>>>(d_in[0], FLAG);

  // fused small-weight conversions (16 segments, prefix-contiguous in SW)
  {
    CvtTab tab;
    const int srcIdx[16] = {4, 6, 8, 10, 11, 12, 13, 14, 16, 18, 19, 20, 21, 22, 23, 24};
    const int starts[17] = {(int)sSA_B_IN, (int)sSA_B_OUT, (int)sCA_B_IN, (int)sCA_B_OUT,
                            (int)sGIW, (int)sGIB, (int)sGTW, (int)sGTB,
                            (int)sEB1, (int)sEB2,
                            (int)sLNQG, (int)sLNQB, (int)sLNCG, (int)sLNCB, (int)sLNFG, (int)sLNFB,
                            (int)SWN};
    for (int c = 0; c < 16; ++c) tab.src[c] = d_in[srcIdx[c]];
    for (int c = 0; c < 17; ++c) tab.start[c] = starts[c];
    k_cvt_multi<<<dim3(((int)SWN + 255) / 256), blk, 0, stream>>>(tab, SW, FLAG);
  }

  k_cvt2<<<dim3((int)(FQ / 256)), blk, 0, stream>>>(d_in[0], Q, (int)FQ, FLAG);
  k_cvt2<<<dim3((int)(FIMG / 256)), blk, 0, stream>>>(d_in[1], IMG32, (int)FIMG, FLAG);

  // ---- 1) self-attention ----
  k_ln<<<dim3(B * T), blk, 0, stream>>>(Q, SW + sLNQG, SW + sLNQB, XN);
  k_gemm_sp<false><<<dim3(3 * H / 64, B * T / 64), blk, 0, stream>>>(
      XN, H, d_in[3], 0, H, SW + sSA_B_IN, QKV, 3 * H, B * T, 3 * H, H, FLAG);
  k_attn_tile<<<dim3(T / 64, NH, B), blk, 0, stream>>>(QKV, 3 * H, QKV + H, 3 * H, QKV + 2 * H, 3 * H, AO, T, T);
  k_gemm_sp<true><<<dim3(H / 64, B * T / 64), blk, 0, stream>>>(
      AO, H, d_in[5], 0, H, SW + sSA_B_OUT, Q, H, B * T, H, H, FLAG);

  // ---- 2) cross-attention ----
  k_ln<<<dim3(B * T), blk, 0, stream>>>(Q, SW + sLNCG, SW + sLNCB, XN);
  k_gemm_sp<false><<<dim3(H / 64, B * T / 64), blk, 0, stream>>>(
      XN, H, d_in[7], 0, H, SW + sCA_B_IN, QKV, H, B * T, H, H, FLAG);
  k_gemm_sp<false><<<dim3(2 * H / 64, B * V / 64), blk, 0, stream>>>(
      IMG32, H, d_in[7], (size_t)H * H, H, SW + sCA_B_IN + H, QKV + FQ, 2 * H, B * V, 2 * H, H, FLAG);
  k_attn_tile<<<dim3(T / 64, NH, B), blk, 0, stream>>>(QKV, H, QKV + FQ, 2 * H, QKV + FQ + H, 2 * H, AO, T, V);
  k_gemm_sp<true><<<dim3(H / 64, B * T / 64), blk, 0, stream>>>(
      AO, H, d_in[9], 0, H, SW + sCA_B_OUT, Q, H, B * T, H, H, FLAG);

  // ---- 3) gating (parallel two-stage means; QKV region is dead -> reuse as scratch) ----
  k_mean_part<<<dim3(B * NCHI + B * NCHT), blk, 0, stream>>>(IMG32, d_in[2], FLAG, PART);
  k_mean_fin<<<dim3((2 * B * H) / 256), blk, 0, stream>>>(PART, CTXI, CTXT);
  k_gate<<<dim3(B * T), blk, 0, stream>>>(Q, CTXI, SW + sGTW, SW + sGTB, PRT, T);
  k_gate<<<dim3(B * V), blk, 0, stream>>>(IMG32, CTXT, SW + sGIW, SW + sGIB, PRI, V);
  k_zeroi<<<dim3((B * T + B * V + 255) / 256), blk, 0, stream>>>(CNT_T, B * T + B * V);

  // ---- 4) top-k for BOTH streams (one dispatch, wave-parallel, barrier-free) ----
  k_topk2<<<dim3(16), blk, 0, stream>>>(PRT, PRI, PAIRS_T, PAIRS_I, CNT_T, CNT_I);

  // ---- 5) text MoE (MFMA) ----
  k_ln<<<dim3(B * T), blk, 0, stream>>>(Q, SW + sLNFG, SW + sLNFB, XN);
  k_zerof<<<dim3((int)(FQ / 256)), blk, 0, stream>>>(AO, (int)FQ);
  k_moe_up_mfma<<<dim3(I / 64, PBT / 64, E), blk, 0, stream>>>(
      XN, B * T, PAIRS_T, PBT, (const float*)d_in[15], (const float*)d_in[16], HBu);
  k_moe_down_mfma<<<dim3(H / 64, PBT / 64, E), blk, 0, stream>>>(
      HBu, B * T, PAIRS_T, PBT, (const float*)d_in[17], (const float*)d_in[18], AO);
  k_final<<<dim3((int)(FQ / 256)), blk, 0, stream>>>(Q, AO, CNT_T, out, (int)FQ);

  // ---- 6) image MoE (MFMA) ----
  k_zerof<<<dim3((int)(FIMG / 256)), blk, 0, stream>>>(AO, (int)FIMG);
  k_moe_up_mfma<<<dim3(I / 64, (PBI + 63) / 64, E), blk, 0, stream>>>(
      IMG32, B * V, PAIRS_I, PBI, (const float*)d_in[15], (const float*)d_in[16], HBu);
  k_moe_down_mfma<<<dim3(H / 64, (PBI + 63) / 64, E), blk, 0, stream>>>(
      HBu, B * V, PAIRS_I, PBI, (const float*)d_in[17], (const float*)d_in[18], AO);
  k_final<<<dim3((int)(FIMG / 256)), blk, 0, stream>>>(IMG32, AO, CNT_I, out + FQ, (int)FIMG);
}